// Round 6
// baseline (1285.392 us; speedup 1.0000x reference)
//
#include <hip/hip_runtime.h>
#include <hip/hip_cooperative_groups.h>

#define NNODE 50000
#define NEDGE 800000
#define NTOT  (NEDGE + NNODE)   // 850000 edges incl. self loops
#define NB_SCAN 49              // ceil(50000/1024)  (fallback path)
#define NCHUNK 196              // ceil(50000/256)   (mega scan)
#define NGEMM 1564              // 782 row-blocks x 2 col-halves

namespace cg = cooperative_groups;

typedef __attribute__((ext_vector_type(8))) short bf16x8;
typedef __attribute__((ext_vector_type(4))) float f32x4;
union U4B8 { uint4 u; bf16x8 b; };

// ---- bf16 helpers (storage-only; all math in fp32) ----
__device__ __forceinline__ unsigned short f2bf(float f) {
  union { float f; unsigned u; } v; v.f = f;
  unsigned r = v.u + 0x7FFFu + ((v.u >> 16) & 1u);   // RN-even
  return (unsigned short)(r >> 16);
}
__device__ __forceinline__ float bflo(unsigned u) {
  union { unsigned u; float f; } v; v.u = u << 16; return v.f;
}
__device__ __forceinline__ float bfhi(unsigned u) {
  union { unsigned u; float f; } v; v.u = u & 0xFFFF0000u; return v.f;
}
__device__ __forceinline__ unsigned packbf(float a, float b) {
  return (unsigned)f2bf(a) | ((unsigned)f2bf(b) << 16);
}

// ---- prep: W1 -> bf16 transposed [256][128] + zero deg (one dispatch) ----
__global__ __launch_bounds__(256) void k_prep(const float* __restrict__ W1,
                                              unsigned short* __restrict__ W1bT,
                                              int* __restrict__ deg) {
  const int b = (int)blockIdx.x;
  if (b < 32) {
    int flat = b * 256 + threadIdx.x;   // 8192 total
    int k = flat >> 6, c4 = (flat & 63) << 2;
    float4 v = *(const float4*)(W1 + k * 256 + c4);
    W1bT[(c4 + 0) * 128 + k] = f2bf(v.x);
    W1bT[(c4 + 1) * 128 + k] = f2bf(v.y);
    W1bT[(c4 + 2) * 128 + k] = f2bf(v.z);
    W1bT[(c4 + 3) * 128 + k] = f2bf(v.w);
  } else {
    int i = (b - 32) * 256 + threadIdx.x;
    if (i < NNODE) deg[i] = 0;
  }
}

// ---- fused: MFMA GEMM (blocks < NGEMM) + degree histogram (rest) ----
__global__ __launch_bounds__(256) void k_gemm_deg(
    const float* __restrict__ x, const unsigned short* __restrict__ W1bT,
    const float* __restrict__ a_s1, const float* __restrict__ a_d1,
    unsigned short* __restrict__ h1b, float* __restrict__ als1,
    float* __restrict__ ald1, const int* __restrict__ ei,
    int* __restrict__ deg) {
  __shared__ unsigned short xs[64 * 136];
  if ((int)blockIdx.x >= NGEMM) {
    int i = ((int)blockIdx.x - NGEMM) * 256 + threadIdx.x;
    if (i < NTOT) {
      int d = (i < NEDGE) ? ei[NEDGE + i] : (i - NEDGE);
      atomicAdd(deg + d, 1);
    }
    return;
  }
  const int t = threadIdx.x;
  const int rb = (int)blockIdx.x >> 1, nhalf = (int)blockIdx.x & 1;
  const int grow0 = rb * 64;
#pragma unroll
  for (int i = 0; i < 8; ++i) {
    int f = t + i * 256;
    int row = f >> 5, c4 = (f & 31) << 2;
    int gr = grow0 + row;
    float4 v = make_float4(0.f, 0.f, 0.f, 0.f);
    if (gr < NNODE) v = *(const float4*)(x + gr * 128 + c4);
    *(uint2*)(xs + row * 136 + c4) = make_uint2(packbf(v.x, v.y), packbf(v.z, v.w));
  }
  const int wid = t >> 6, lane = t & 63;
  const int wrow = (wid >> 1) * 32;
  const int head = nhalf * 2 + (wid & 1);
  const int c_lo = lane & 15, g = lane >> 4;
  U4B8 bfr[4][4];
#pragma unroll
  for (int nr = 0; nr < 4; ++nr) {
    int c = head * 64 + nr * 16 + c_lo;
#pragma unroll
    for (int ks = 0; ks < 4; ++ks)
      bfr[nr][ks].u = *(const uint4*)(W1bT + c * 128 + ks * 32 + g * 8);
  }
  __syncthreads();
  U4B8 afr[2][4];
#pragma unroll
  for (int mr = 0; mr < 2; ++mr)
#pragma unroll
    for (int ks = 0; ks < 4; ++ks)
      afr[mr][ks].u = *(const uint4*)(xs + (wrow + mr * 16 + c_lo) * 136 + ks * 32 + g * 8);
  f32x4 acc[2][4];
#pragma unroll
  for (int mr = 0; mr < 2; ++mr)
#pragma unroll
    for (int nr = 0; nr < 4; ++nr) acc[mr][nr] = (f32x4){0.f, 0.f, 0.f, 0.f};
#pragma unroll
  for (int ks = 0; ks < 4; ++ks)
#pragma unroll
    for (int mr = 0; mr < 2; ++mr)
#pragma unroll
      for (int nr = 0; nr < 4; ++nr)
        acc[mr][nr] = __builtin_amdgcn_mfma_f32_16x16x32_bf16(
            afr[mr][ks].b, bfr[nr][ks].b, acc[mr][nr], 0, 0, 0);
  float as_v[4], ad_v[4];
#pragma unroll
  for (int nr = 0; nr < 4; ++nr) {
    as_v[nr] = a_s1[head * 64 + nr * 16 + c_lo];
    ad_v[nr] = a_d1[head * 64 + nr * 16 + c_lo];
  }
  float ps[2][4], pd[2][4];
#pragma unroll
  for (int mr = 0; mr < 2; ++mr)
#pragma unroll
    for (int r = 0; r < 4; ++r) {
      float s = 0.f, dsum = 0.f;
#pragma unroll
      for (int nr = 0; nr < 4; ++nr) {
        s += acc[mr][nr][r] * as_v[nr];
        dsum += acc[mr][nr][r] * ad_v[nr];
      }
      ps[mr][r] = s; pd[mr][r] = dsum;
    }
#pragma unroll
  for (int m = 1; m < 16; m <<= 1)
#pragma unroll
    for (int mr = 0; mr < 2; ++mr)
#pragma unroll
      for (int r = 0; r < 4; ++r) {
        ps[mr][r] += __shfl_xor(ps[mr][r], m, 64);
        pd[mr][r] += __shfl_xor(pd[mr][r], m, 64);
      }
  if (c_lo == 0) {
#pragma unroll
    for (int mr = 0; mr < 2; ++mr)
#pragma unroll
      for (int r = 0; r < 4; ++r) {
        int node = grow0 + wrow + mr * 16 + g * 4 + r;
        if (node < NNODE) {
          als1[node * 4 + head] = ps[mr][r];
          ald1[node * 4 + head] = pd[mr][r];
        }
      }
  }
  __syncthreads();
  unsigned short* tb = xs + wid * 2048;
#pragma unroll
  for (int mr = 0; mr < 2; ++mr)
#pragma unroll
    for (int nr = 0; nr < 4; ++nr)
#pragma unroll
      for (int r = 0; r < 4; ++r)
        tb[(mr * 16 + g * 4 + r) * 64 + nr * 16 + c_lo] = f2bf(acc[mr][nr][r]);
#pragma unroll
  for (int i = 0; i < 4; ++i) {
    int unit = i * 64 + lane;
    int row = unit >> 3, cS = (unit & 7) * 8;
    int node = grow0 + wrow + row;
    if (node < NNODE) {
      uint4 v = *(const uint4*)(tb + unit * 8);
      *(uint4*)(h1b + (size_t)node * 256 + nhalf * 128 + (wid & 1) * 64 + cS) = v;
    }
  }
}

// ================= cooperative mega-kernel: scan+scatter+agg1+agg2 ========
__device__ __forceinline__ void gsync() {
  __threadfence();
  cg::this_grid().sync();
  __threadfence();
}

__global__ __launch_bounds__(256, 8) void k_mega(
    const int* __restrict__ deg, int* __restrict__ rowp, int* __restrict__ curs,
    int* __restrict__ esrc, const int* __restrict__ ei,
    const unsigned short* __restrict__ h1b, const float* __restrict__ als1,
    const float* __restrict__ ald1, const float* __restrict__ b1,
    const float* __restrict__ W2, const float* __restrict__ a_s2,
    const float* __restrict__ a_d2, float4* __restrict__ h2c,
    const float* __restrict__ b2, float* __restrict__ out,
    int* __restrict__ chunkSum) {
  __shared__ int lds4[4];
  const int t = threadIdx.x;
  const int lane = t & 63, wid = t >> 6;
  const int nthr = (int)gridDim.x * 256;

  // ---- phase A: per-chunk (256) inclusive scan of deg -> rowp[idx+1] ----
  for (int c = (int)blockIdx.x; c < NCHUNK; c += (int)gridDim.x) {
    int idx = c * 256 + t;
    int v = (idx < NNODE) ? deg[idx] : 0;
    int sv = v;
#pragma unroll
    for (int off = 1; off < 64; off <<= 1) {
      int n = __shfl_up(sv, off, 64);
      if (lane >= off) sv += n;
    }
    if (lane == 63) lds4[wid] = sv;
    __syncthreads();
    int add = 0;
#pragma unroll
    for (int p = 0; p < 3; ++p) if (wid > p) add += lds4[p];
    sv += add;
    if (idx < NNODE) rowp[idx + 1] = sv;
    if (t == 255) chunkSum[c] = sv;
    __syncthreads();
  }
  gsync();
  // ---- phase B: add chunk prefixes (each block redundantly reduces) ----
  for (int c = (int)blockIdx.x; c < NCHUNK; c += (int)gridDim.x) {
    int v = (t < c) ? chunkSum[t] : 0;   // t<c<=195<256
#pragma unroll
    for (int m = 32; m >= 1; m >>= 1) v += __shfl_xor(v, m, 64);
    if (lane == 0) lds4[wid] = v;
    __syncthreads();
    int prefix = lds4[0] + lds4[1] + lds4[2] + lds4[3];
    int idx = c * 256 + t;
    if (idx < NNODE) {
      int incl = rowp[idx + 1] + prefix;
      rowp[idx + 1] = incl;
      curs[idx] = incl - deg[idx];
      if (idx == 0) rowp[0] = 0;
    }
    __syncthreads();
  }
  gsync();
  // ---- phase C: scatter edges into CSR ----
  for (int i = (int)blockIdx.x * 256 + t; i < NTOT; i += nthr) {
    int s, d;
    if (i < NEDGE) { s = ei[i]; d = ei[NEDGE + i]; }
    else           { s = i - NEDGE; d = s; }
    int pos = atomicAdd(curs + d, 1);
    esrc[pos] = s;
  }
  gsync();
  // ---- phase D: layer-1 aggregate + bias/relu + layer-2 linear/logits ----
  {
    const int nwaves = (int)gridDim.x * 4;
    const int half = lane >> 5, cl = lane & 31;
    const int head = cl >> 3;
    const int c0 = cl * 8;
    for (int d = (int)blockIdx.x * 4 + wid; d < NNODE; d += nwaves) {
      const float ald = ald1[d * 4 + head];
      const int begin = rowp[d], end = rowp[d + 1];
      float acc[8];
#pragma unroll
      for (int i = 0; i < 8; ++i) acc[i] = 0.f;
      float S = 0.f;
      int j = begin + half;
      int s = (j < end) ? esrc[j] : -1;
      while (s >= 0) {
        const uint4 hv = *(const uint4*)(h1b + (size_t)s * 256 + cl * 8);
        float e = als1[s * 4 + head] + ald;
        int jn = j + 2;
        int sn = (jn < end) ? esrc[jn] : -1;
        e = fmaxf(e, 0.2f * e);           // leaky relu
        float wgt = __expf(e);
        S += wgt;
        acc[0] += wgt * bflo(hv.x); acc[1] += wgt * bfhi(hv.x);
        acc[2] += wgt * bflo(hv.y); acc[3] += wgt * bfhi(hv.y);
        acc[4] += wgt * bflo(hv.z); acc[5] += wgt * bfhi(hv.z);
        acc[6] += wgt * bflo(hv.w); acc[7] += wgt * bfhi(hv.w);
        j = jn; s = sn;
      }
      S += __shfl_xor(S, 32, 64);
#pragma unroll
      for (int i = 0; i < 8; ++i) acc[i] += __shfl_xor(acc[i], 32, 64);
      const float inv = 1.f / S;
      float4 ba = *(const float4*)(b1 + c0);
      float4 bb = *(const float4*)(b1 + c0 + 4);
      float bias[8] = {ba.x, ba.y, ba.z, ba.w, bb.x, bb.y, bb.z, bb.w};
      float4 w0 = *(const float4*)(W2 + c0 * 2);
      float4 w1 = *(const float4*)(W2 + c0 * 2 + 4);
      float4 w2 = *(const float4*)(W2 + c0 * 2 + 8);
      float4 w3 = *(const float4*)(W2 + c0 * 2 + 12);
      float wa[16] = {w0.x, w0.y, w0.z, w0.w, w1.x, w1.y, w1.z, w1.w,
                      w2.x, w2.y, w2.z, w2.w, w3.x, w3.y, w3.z, w3.w};
      float p0 = 0.f, p1 = 0.f;
#pragma unroll
      for (int i = 0; i < 8; ++i) {
        float v = acc[i] * inv + bias[i];
        v = v > 0.f ? v : 0.f;
        p0 += v * wa[2 * i];
        p1 += v * wa[2 * i + 1];
      }
#pragma unroll
      for (int m = 1; m < 32; m <<= 1) {
        p0 += __shfl_xor(p0, m, 64);
        p1 += __shfl_xor(p1, m, 64);
      }
      if (lane == 0) {
        h2c[d] = make_float4(p0, p1,
                             p0 * a_s2[0] + p1 * a_s2[1],
                             p0 * a_d2[0] + p1 * a_d2[1]);
      }
    }
  }
  gsync();
  // ---- phase E: layer-2 aggregate -> out (thread per dst) ----
  for (int d = (int)blockIdx.x * 256 + t; d < NNODE; d += nthr) {
    const float ald = h2c[d].w;
    const int begin = rowp[d], end = rowp[d + 1];
    float S = 0.f, a0 = 0.f, a1 = 0.f;
    for (int j = begin; j < end; ++j) {
      int s = esrc[j];
      float4 v = h2c[s];
      float e = v.z + ald;
      e = fmaxf(e, 0.2f * e);
      float wgt = __expf(e);
      S += wgt;
      a0 += wgt * v.x;
      a1 += wgt * v.y;
    }
    float inv = 1.f / S;
    out[d * 2 + 0] = a0 * inv + b2[0];
    out[d * 2 + 1] = a1 * inv + b2[1];
  }
}

// ================= fallback path (R5 kernels, used if coop launch fails) ===
__global__ __launch_bounds__(1024) void k_scan1(const int* __restrict__ deg,
                                                int* __restrict__ rowptr,
                                                int* __restrict__ bsum) {
  __shared__ int sh[1024];
  const int t = threadIdx.x;
  const int idx = (int)blockIdx.x * 1024 + t;
  int v = (idx < NNODE) ? deg[idx] : 0;
  sh[t] = v;
  __syncthreads();
#pragma unroll
  for (int off = 1; off < 1024; off <<= 1) {
    int add = (t >= off) ? sh[t - off] : 0;
    __syncthreads();
    sh[t] += add;
    __syncthreads();
  }
  if (idx < NNODE) rowptr[idx + 1] = sh[t];
  if (t == 1023) bsum[blockIdx.x] = sh[1023];
}

__global__ __launch_bounds__(256) void k_scan23(const int* __restrict__ deg,
                                                int* __restrict__ rowptr,
                                                const int* __restrict__ bsum,
                                                int* __restrict__ cursor) {
  __shared__ int boff[64];
  const int t = threadIdx.x;
  if (t < 64) {
    int v = (t < NB_SCAN) ? bsum[t] : 0;
    int orig = v;
#pragma unroll
    for (int off = 1; off < 64; off <<= 1) {
      int n = __shfl_up(v, off, 64);
      if (t >= off) v += n;
    }
    boff[t] = v - orig;
  }
  __syncthreads();
  int idx = (int)blockIdx.x * 256 + t;
  if (idx < NNODE) {
    int incl = rowptr[idx + 1] + boff[idx >> 10];
    rowptr[idx + 1] = incl;
    cursor[idx] = incl - deg[idx];
    if (idx == 0) rowptr[0] = 0;
  }
}

__global__ void k_scatter(const int* __restrict__ ei, int* __restrict__ cursor,
                          int* __restrict__ esrc) {
  int i = (int)blockIdx.x * blockDim.x + threadIdx.x;
  if (i >= NTOT) return;
  int s, d;
  if (i < NEDGE) { s = ei[i]; d = ei[NEDGE + i]; }
  else           { s = i - NEDGE; d = s; }
  int pos = atomicAdd(cursor + d, 1);
  esrc[pos] = s;
}

__global__ __launch_bounds__(256) void k_agg1(
    const unsigned short* __restrict__ h1b, const float* __restrict__ als1,
    const float* __restrict__ ald1, const int* __restrict__ rowptr,
    const int* __restrict__ esrc, const float* __restrict__ b1,
    const float* __restrict__ W2, const float* __restrict__ a_s2,
    const float* __restrict__ a_d2, float4* __restrict__ h2c) {
  const int w = threadIdx.x >> 6, lane = threadIdx.x & 63;
  const int d = (int)blockIdx.x * 4 + w;
  const int half = lane >> 5, cl = lane & 31;
  const int head = cl >> 3;
  const float ald = ald1[d * 4 + head];
  const int begin = rowptr[d], end = rowptr[d + 1];
  float acc[8];
#pragma unroll
  for (int i = 0; i < 8; ++i) acc[i] = 0.f;
  float S = 0.f;
  int j = begin + half;
  int s = (j < end) ? esrc[j] : -1;
  while (s >= 0) {
    const uint4 hv = *(const uint4*)(h1b + (size_t)s * 256 + cl * 8);
    float e = als1[s * 4 + head] + ald;
    int jn = j + 2;
    int sn = (jn < end) ? esrc[jn] : -1;
    e = fmaxf(e, 0.2f * e);
    float wgt = __expf(e);
    S += wgt;
    acc[0] += wgt * bflo(hv.x); acc[1] += wgt * bfhi(hv.x);
    acc[2] += wgt * bflo(hv.y); acc[3] += wgt * bfhi(hv.y);
    acc[4] += wgt * bflo(hv.z); acc[5] += wgt * bfhi(hv.z);
    acc[6] += wgt * bflo(hv.w); acc[7] += wgt * bfhi(hv.w);
    j = jn; s = sn;
  }
  S += __shfl_xor(S, 32, 64);
#pragma unroll
  for (int i = 0; i < 8; ++i) acc[i] += __shfl_xor(acc[i], 32, 64);
  const float inv = 1.f / S;
  const int c0 = cl * 8;
  float4 ba = *(const float4*)(b1 + c0);
  float4 bb = *(const float4*)(b1 + c0 + 4);
  float bias[8] = {ba.x, ba.y, ba.z, ba.w, bb.x, bb.y, bb.z, bb.w};
  float4 w0 = *(const float4*)(W2 + c0 * 2);
  float4 w1 = *(const float4*)(W2 + c0 * 2 + 4);
  float4 w2 = *(const float4*)(W2 + c0 * 2 + 8);
  float4 w3 = *(const float4*)(W2 + c0 * 2 + 12);
  float wa[16] = {w0.x, w0.y, w0.z, w0.w, w1.x, w1.y, w1.z, w1.w,
                  w2.x, w2.y, w2.z, w2.w, w3.x, w3.y, w3.z, w3.w};
  float p0 = 0.f, p1 = 0.f;
#pragma unroll
  for (int i = 0; i < 8; ++i) {
    float v = acc[i] * inv + bias[i];
    v = v > 0.f ? v : 0.f;
    p0 += v * wa[2 * i];
    p1 += v * wa[2 * i + 1];
  }
#pragma unroll
  for (int m = 1; m < 32; m <<= 1) {
    p0 += __shfl_xor(p0, m, 64);
    p1 += __shfl_xor(p1, m, 64);
  }
  if (lane == 0) {
    h2c[d] = make_float4(p0, p1,
                         p0 * a_s2[0] + p1 * a_s2[1],
                         p0 * a_d2[0] + p1 * a_d2[1]);
  }
}

__global__ __launch_bounds__(256) void k_agg2(
    const float4* __restrict__ h2c, const int* __restrict__ rowptr,
    const int* __restrict__ esrc, const float* __restrict__ b2,
    float* __restrict__ out) {
  int d = (int)blockIdx.x * 256 + threadIdx.x;
  if (d >= NNODE) return;
  const float ald = h2c[d].w;
  const int begin = rowptr[d], end = rowptr[d + 1];
  float S = 0.f, a0 = 0.f, a1 = 0.f;
  for (int j = begin; j < end; ++j) {
    int s = esrc[j];
    float4 v = h2c[s];
    float e = v.z + ald;
    e = fmaxf(e, 0.2f * e);
    float wgt = __expf(e);
    S += wgt;
    a0 += wgt * v.x;
    a1 += wgt * v.y;
  }
  float inv = 1.f / S;
  out[d * 2 + 0] = a0 * inv + b2[0];
  out[d * 2 + 1] = a1 * inv + b2[1];
}

static inline size_t algn(size_t x) { return (x + 255) & ~(size_t)255; }

extern "C" void kernel_launch(void* const* d_in, const int* in_sizes, int n_in,
                              void* d_out, int out_size, void* d_ws, size_t ws_size,
                              hipStream_t stream) {
  const float* x    = (const float*)d_in[0];
  const int*   ei   = (const int*)d_in[1];
  const float* W1   = (const float*)d_in[2];
  const float* a_s1 = (const float*)d_in[3];
  const float* a_d1 = (const float*)d_in[4];
  const float* b1   = (const float*)d_in[5];
  const float* W2   = (const float*)d_in[6];
  const float* a_s2 = (const float*)d_in[7];
  const float* a_d2 = (const float*)d_in[8];
  const float* b2   = (const float*)d_in[9];
  float* out = (float*)d_out;

  char* w = (char*)d_ws;
  size_t o = 0;
  unsigned short* h1b = (unsigned short*)(w + o); o += algn((size_t)NNODE * 256 * 2);
  unsigned short* W1bT = (unsigned short*)(w + o); o += algn((size_t)256 * 128 * 2);
  float* als1 = (float*)(w + o); o += algn((size_t)NNODE * 4 * 4);
  float* ald1 = (float*)(w + o); o += algn((size_t)NNODE * 4 * 4);
  int*   deg  = (int*)(w + o);   o += algn((size_t)NNODE * 4);
  int*   rowp = (int*)(w + o);   o += algn((size_t)(NNODE + 1) * 4);
  int*   curs = (int*)(w + o);   o += algn((size_t)NNODE * 4);
  int*   esrc = (int*)(w + o);   o += algn((size_t)NTOT * 4);
  int*   bsum = (int*)(w + o);   o += 256;       // fallback scan sums
  int*   csum = (int*)(w + o);   o += 1024;      // mega chunk sums
  float4* h2c = (float4*)(w + o); o += algn((size_t)NNODE * 16);
  (void)ws_size; (void)n_in; (void)in_sizes; (void)out_size;

  k_prep<<<dim3(32 + 196), dim3(256), 0, stream>>>(W1, W1bT, deg);
  k_gemm_deg<<<dim3(NGEMM + (NTOT + 255) / 256), dim3(256), 0, stream>>>(
      x, W1bT, a_s1, a_d1, h1b, als1, ald1, ei, deg);

  // cooperative mega kernel, clamped to guaranteed-resident grid
  int maxAct = 0;
  if (hipOccupancyMaxActiveBlocksPerMultiprocessor(&maxAct, k_mega, 256, 0)
          != hipSuccess || maxAct < 1)
    maxAct = 4;
  unsigned grid = (unsigned)maxAct * 256u;
  if (grid > 2048u) grid = 2048u;

  void* args[16] = {
      (void*)&deg, (void*)&rowp, (void*)&curs, (void*)&esrc, (void*)&ei,
      (void*)&h1b, (void*)&als1, (void*)&ald1, (void*)&b1, (void*)&W2,
      (void*)&a_s2, (void*)&a_d2, (void*)&h2c, (void*)&b2, (void*)&out,
      (void*)&csum};
  hipError_t ce = hipLaunchCooperativeKernel((const void*)k_mega, dim3(grid),
                                             dim3(256), args, 0, stream);
  if (ce != hipSuccess) {
    // fallback: R5 pipeline (separate dispatches)
    k_scan1<<<dim3(NB_SCAN), dim3(1024), 0, stream>>>(deg, rowp, bsum);
    k_scan23<<<dim3((NNODE + 255) / 256), dim3(256), 0, stream>>>(deg, rowp, bsum, curs);
    k_scatter<<<dim3((NTOT + 255) / 256), dim3(256), 0, stream>>>(ei, curs, esrc);
    k_agg1<<<dim3(12500), dim3(256), 0, stream>>>(h1b, als1, ald1, rowp, esrc, b1,
                                                  W2, a_s2, a_d2, h2c);
    k_agg2<<<dim3((NNODE + 255) / 256), dim3(256), 0, stream>>>(h2c, rowp, esrc, b2, out);
  }
}

// Round 7
// 250.989 us; speedup vs baseline: 5.1213x; 5.1213x over previous
//
#include <hip/hip_runtime.h>

#define NNODE 50000
#define NEDGE 800000
#define NTOT  (NEDGE + NNODE)   // 850000 edges incl. self loops
#define NB_SCAN 49              // ceil(50000/1024)
#define NGEMM 1564              // 782 row-blocks x 2 col-halves

typedef __attribute__((ext_vector_type(8))) short bf16x8;
typedef __attribute__((ext_vector_type(4))) float f32x4;
union U4B8 { uint4 u; bf16x8 b; };

// ---- bf16 helpers (storage-only; all math in fp32) ----
__device__ __forceinline__ unsigned short f2bf(float f) {
  union { float f; unsigned u; } v; v.f = f;
  unsigned r = v.u + 0x7FFFu + ((v.u >> 16) & 1u);   // RN-even
  return (unsigned short)(r >> 16);
}
__device__ __forceinline__ float bflo(unsigned u) {
  union { unsigned u; float f; } v; v.u = u << 16; return v.f;
}
__device__ __forceinline__ float bfhi(unsigned u) {
  union { unsigned u; float f; } v; v.u = u & 0xFFFF0000u; return v.f;
}
__device__ __forceinline__ unsigned packbf(float a, float b) {
  return (unsigned)f2bf(a) | ((unsigned)f2bf(b) << 16);
}

// ---- prep: W1 -> bf16 transposed [256][128] + zero deg (one dispatch) ----
__global__ __launch_bounds__(256) void k_prep(const float* __restrict__ W1,
                                              unsigned short* __restrict__ W1bT,
                                              int* __restrict__ deg) {
  const int b = (int)blockIdx.x;
  if (b < 32) {
    int flat = b * 256 + threadIdx.x;   // 8192 total
    int k = flat >> 6, c4 = (flat & 63) << 2;
    float4 v = *(const float4*)(W1 + k * 256 + c4);
    W1bT[(c4 + 0) * 128 + k] = f2bf(v.x);
    W1bT[(c4 + 1) * 128 + k] = f2bf(v.y);
    W1bT[(c4 + 2) * 128 + k] = f2bf(v.z);
    W1bT[(c4 + 3) * 128 + k] = f2bf(v.w);
  } else {
    int i = (b - 32) * 256 + threadIdx.x;
    if (i < NNODE) deg[i] = 0;
  }
}

// ---- fused: MFMA GEMM (blocks < NGEMM) + degree histogram (+rank) --------
__global__ __launch_bounds__(256) void k_gemm_deg(
    const float* __restrict__ x, const unsigned short* __restrict__ W1bT,
    const float* __restrict__ a_s1, const float* __restrict__ a_d1,
    unsigned short* __restrict__ h1b, float* __restrict__ als1,
    float* __restrict__ ald1, const int* __restrict__ ei,
    int* __restrict__ deg, int* __restrict__ rank) {
  __shared__ unsigned short xs[64 * 136];
  if ((int)blockIdx.x >= NGEMM) {
    int i = ((int)blockIdx.x - NGEMM) * 256 + threadIdx.x;
    if (i < NTOT) {
      int d = (i < NEDGE) ? ei[NEDGE + i] : (i - NEDGE);
      rank[i] = atomicAdd(deg + d, 1);   // rank within dst bucket
    }
    return;
  }
  const int t = threadIdx.x;
  const int rb = (int)blockIdx.x >> 1, nhalf = (int)blockIdx.x & 1;
  const int grow0 = rb * 64;
#pragma unroll
  for (int i = 0; i < 8; ++i) {
    int f = t + i * 256;
    int row = f >> 5, c4 = (f & 31) << 2;
    int gr = grow0 + row;
    float4 v = make_float4(0.f, 0.f, 0.f, 0.f);
    if (gr < NNODE) v = *(const float4*)(x + gr * 128 + c4);
    *(uint2*)(xs + row * 136 + c4) = make_uint2(packbf(v.x, v.y), packbf(v.z, v.w));
  }
  const int wid = t >> 6, lane = t & 63;
  const int wrow = (wid >> 1) * 32;
  const int head = nhalf * 2 + (wid & 1);
  const int c_lo = lane & 15, g = lane >> 4;
  U4B8 bfr[4][4];
#pragma unroll
  for (int nr = 0; nr < 4; ++nr) {
    int c = head * 64 + nr * 16 + c_lo;
#pragma unroll
    for (int ks = 0; ks < 4; ++ks)
      bfr[nr][ks].u = *(const uint4*)(W1bT + c * 128 + ks * 32 + g * 8);
  }
  __syncthreads();
  U4B8 afr[2][4];
#pragma unroll
  for (int mr = 0; mr < 2; ++mr)
#pragma unroll
    for (int ks = 0; ks < 4; ++ks)
      afr[mr][ks].u = *(const uint4*)(xs + (wrow + mr * 16 + c_lo) * 136 + ks * 32 + g * 8);
  f32x4 acc[2][4];
#pragma unroll
  for (int mr = 0; mr < 2; ++mr)
#pragma unroll
    for (int nr = 0; nr < 4; ++nr) acc[mr][nr] = (f32x4){0.f, 0.f, 0.f, 0.f};
#pragma unroll
  for (int ks = 0; ks < 4; ++ks)
#pragma unroll
    for (int mr = 0; mr < 2; ++mr)
#pragma unroll
      for (int nr = 0; nr < 4; ++nr)
        acc[mr][nr] = __builtin_amdgcn_mfma_f32_16x16x32_bf16(
            afr[mr][ks].b, bfr[nr][ks].b, acc[mr][nr], 0, 0, 0);
  float as_v[4], ad_v[4];
#pragma unroll
  for (int nr = 0; nr < 4; ++nr) {
    as_v[nr] = a_s1[head * 64 + nr * 16 + c_lo];
    ad_v[nr] = a_d1[head * 64 + nr * 16 + c_lo];
  }
  float ps[2][4], pd[2][4];
#pragma unroll
  for (int mr = 0; mr < 2; ++mr)
#pragma unroll
    for (int r = 0; r < 4; ++r) {
      float s = 0.f, dsum = 0.f;
#pragma unroll
      for (int nr = 0; nr < 4; ++nr) {
        s += acc[mr][nr][r] * as_v[nr];
        dsum += acc[mr][nr][r] * ad_v[nr];
      }
      ps[mr][r] = s; pd[mr][r] = dsum;
    }
#pragma unroll
  for (int m = 1; m < 16; m <<= 1)
#pragma unroll
    for (int mr = 0; mr < 2; ++mr)
#pragma unroll
      for (int r = 0; r < 4; ++r) {
        ps[mr][r] += __shfl_xor(ps[mr][r], m, 64);
        pd[mr][r] += __shfl_xor(pd[mr][r], m, 64);
      }
  if (c_lo == 0) {
#pragma unroll
    for (int mr = 0; mr < 2; ++mr)
#pragma unroll
      for (int r = 0; r < 4; ++r) {
        int node = grow0 + wrow + mr * 16 + g * 4 + r;
        if (node < NNODE) {
          als1[node * 4 + head] = ps[mr][r];
          ald1[node * 4 + head] = pd[mr][r];
        }
      }
  }
  __syncthreads();
  unsigned short* tb = xs + wid * 2048;
#pragma unroll
  for (int mr = 0; mr < 2; ++mr)
#pragma unroll
    for (int nr = 0; nr < 4; ++nr)
#pragma unroll
      for (int r = 0; r < 4; ++r)
        tb[(mr * 16 + g * 4 + r) * 64 + nr * 16 + c_lo] = f2bf(acc[mr][nr][r]);
#pragma unroll
  for (int i = 0; i < 4; ++i) {
    int unit = i * 64 + lane;
    int row = unit >> 3, cS = (unit & 7) * 8;
    int node = grow0 + wrow + row;
    if (node < NNODE) {
      uint4 v = *(const uint4*)(tb + unit * 8);
      *(uint4*)(h1b + (size_t)node * 256 + nhalf * 128 + (wid & 1) * 64 + cS) = v;
    }
  }
}

// ---------------- CSR scan ----------------
__global__ __launch_bounds__(1024) void k_scan1(const int* __restrict__ deg,
                                                int* __restrict__ rowptr,
                                                int* __restrict__ bsum) {
  __shared__ int sh[1024];
  const int t = threadIdx.x;
  const int idx = (int)blockIdx.x * 1024 + t;
  int v = (idx < NNODE) ? deg[idx] : 0;
  sh[t] = v;
  __syncthreads();
#pragma unroll
  for (int off = 1; off < 1024; off <<= 1) {
    int add = (t >= off) ? sh[t - off] : 0;
    __syncthreads();
    sh[t] += add;
    __syncthreads();
  }
  if (idx < NNODE) rowptr[idx + 1] = sh[t];
  if (t == 1023) bsum[blockIdx.x] = sh[1023];
}

// block-local wave scan of the 49 block sums; finalize rowptr
__global__ __launch_bounds__(256) void k_scan23(int* __restrict__ rowptr,
                                                const int* __restrict__ bsum) {
  __shared__ int boff[64];
  const int t = threadIdx.x;
  if (t < 64) {
    int v = (t < NB_SCAN) ? bsum[t] : 0;
    int orig = v;
#pragma unroll
    for (int off = 1; off < 64; off <<= 1) {
      int n = __shfl_up(v, off, 64);
      if (t >= off) v += n;
    }
    boff[t] = v - orig;   // exclusive prefix
  }
  __syncthreads();
  int idx = (int)blockIdx.x * 256 + t;
  if (idx < NNODE) {
    rowptr[idx + 1] += boff[idx >> 10];
    if (idx == 0) rowptr[0] = 0;
  }
}

// ---- scatter, atomic-free: pos = rowptr[d] + rank[i] ----
__global__ void k_scatter(const int* __restrict__ ei,
                          const int* __restrict__ rowptr,
                          const int* __restrict__ rank,
                          int* __restrict__ esrc) {
  int i = (int)blockIdx.x * blockDim.x + threadIdx.x;
  if (i >= NTOT) return;
  int s, d;
  if (i < NEDGE) { s = ei[i]; d = ei[NEDGE + i]; }
  else           { s = i - NEDGE; d = s; }
  esrc[rowptr[d] + rank[i]] = s;
}

// ------- layer-1 aggregate + bias + relu + layer-2 linear/logits -------
// one wave per dst node; QUARTER-wave per edge (4 edge chains + 8 gathers
// in flight per wave). lane: q = lane>>4 edge slot, cl = lane&15 owns 16
// channels (32B), head = cl>>2.
__global__ __launch_bounds__(256) void k_agg1(
    const unsigned short* __restrict__ h1b, const float* __restrict__ als1,
    const float* __restrict__ ald1, const int* __restrict__ rowptr,
    const int* __restrict__ esrc, const float* __restrict__ b1,
    const float* __restrict__ W2, const float* __restrict__ a_s2,
    const float* __restrict__ a_d2, float4* __restrict__ h2c) {
  const int w = threadIdx.x >> 6, lane = threadIdx.x & 63;
  const int d = (int)blockIdx.x * 4 + w;           // grid = 12500
  const int q = lane >> 4, cl = lane & 15;
  const int head = cl >> 2;
  const float ald = ald1[d * 4 + head];
  const int begin = rowptr[d], end = rowptr[d + 1];
  float acc[16];
#pragma unroll
  for (int i = 0; i < 16; ++i) acc[i] = 0.f;
  float S = 0.f;

  for (int j = begin + q; j < end; j += 4) {
    int s = esrc[j];
    const unsigned short* hp = h1b + (size_t)s * 256 + cl * 16;
    const uint4 hv0 = *(const uint4*)(hp);
    const uint4 hv1 = *(const uint4*)(hp + 8);
    float e = als1[s * 4 + head] + ald;
    e = fmaxf(e, 0.2f * e);               // leaky relu
    float wgt = __expf(e);
    S += wgt;
    acc[0]  += wgt * bflo(hv0.x); acc[1]  += wgt * bfhi(hv0.x);
    acc[2]  += wgt * bflo(hv0.y); acc[3]  += wgt * bfhi(hv0.y);
    acc[4]  += wgt * bflo(hv0.z); acc[5]  += wgt * bfhi(hv0.z);
    acc[6]  += wgt * bflo(hv0.w); acc[7]  += wgt * bfhi(hv0.w);
    acc[8]  += wgt * bflo(hv1.x); acc[9]  += wgt * bfhi(hv1.x);
    acc[10] += wgt * bflo(hv1.y); acc[11] += wgt * bfhi(hv1.y);
    acc[12] += wgt * bflo(hv1.z); acc[13] += wgt * bfhi(hv1.z);
    acc[14] += wgt * bflo(hv1.w); acc[15] += wgt * bfhi(hv1.w);
  }
  // combine the four quarter-waves (same channels, disjoint edges)
  S += __shfl_xor(S, 16, 64);
  S += __shfl_xor(S, 32, 64);
#pragma unroll
  for (int i = 0; i < 16; ++i) {
    acc[i] += __shfl_xor(acc[i], 16, 64);
    acc[i] += __shfl_xor(acc[i], 32, 64);
  }

  const float inv = 1.f / S;
  const int c0 = cl * 16;
  float bias[16];
#pragma unroll
  for (int i = 0; i < 4; ++i) {
    float4 bv = *(const float4*)(b1 + c0 + i * 4);
    bias[4 * i] = bv.x; bias[4 * i + 1] = bv.y;
    bias[4 * i + 2] = bv.z; bias[4 * i + 3] = bv.w;
  }
  float wa[32];
#pragma unroll
  for (int i = 0; i < 8; ++i) {
    float4 wv = *(const float4*)(W2 + c0 * 2 + i * 4);
    wa[4 * i] = wv.x; wa[4 * i + 1] = wv.y;
    wa[4 * i + 2] = wv.z; wa[4 * i + 3] = wv.w;
  }
  float p0 = 0.f, p1 = 0.f;
#pragma unroll
  for (int i = 0; i < 16; ++i) {
    float v = acc[i] * inv + bias[i];
    v = v > 0.f ? v : 0.f;
    p0 += v * wa[2 * i];
    p1 += v * wa[2 * i + 1];
  }
  // reduce across the 16 channel groups (quarter-waves hold identical copies)
#pragma unroll
  for (int m = 1; m < 16; m <<= 1) {
    p0 += __shfl_xor(p0, m, 64);
    p1 += __shfl_xor(p1, m, 64);
  }
  if (lane == 0) {
    h2c[d] = make_float4(p0, p1,
                         p0 * a_s2[0] + p1 * a_s2[1],
                         p0 * a_d2[0] + p1 * a_d2[1]);
  }
}

// ---------------- layer-2 aggregate -> out (thread per dst) ----------------
__global__ __launch_bounds__(256) void k_agg2(
    const float4* __restrict__ h2c, const int* __restrict__ rowptr,
    const int* __restrict__ esrc, const float* __restrict__ b2,
    float* __restrict__ out) {
  int d = (int)blockIdx.x * 256 + threadIdx.x;
  if (d >= NNODE) return;
  const float ald = h2c[d].w;
  const int begin = rowptr[d], end = rowptr[d + 1];
  float S = 0.f, a0 = 0.f, a1 = 0.f;
  for (int j = begin; j < end; ++j) {
    int s = esrc[j];
    float4 v = h2c[s];
    float e = v.z + ald;
    e = fmaxf(e, 0.2f * e);
    float wgt = __expf(e);
    S += wgt;
    a0 += wgt * v.x;
    a1 += wgt * v.y;
  }
  float inv = 1.f / S;
  out[d * 2 + 0] = a0 * inv + b2[0];
  out[d * 2 + 1] = a1 * inv + b2[1];
}

static inline size_t algn(size_t x) { return (x + 255) & ~(size_t)255; }

extern "C" void kernel_launch(void* const* d_in, const int* in_sizes, int n_in,
                              void* d_out, int out_size, void* d_ws, size_t ws_size,
                              hipStream_t stream) {
  const float* x    = (const float*)d_in[0];
  const int*   ei   = (const int*)d_in[1];
  const float* W1   = (const float*)d_in[2];
  const float* a_s1 = (const float*)d_in[3];
  const float* a_d1 = (const float*)d_in[4];
  const float* b1   = (const float*)d_in[5];
  const float* W2   = (const float*)d_in[6];
  const float* a_s2 = (const float*)d_in[7];
  const float* a_d2 = (const float*)d_in[8];
  const float* b2   = (const float*)d_in[9];
  float* out = (float*)d_out;

  char* w = (char*)d_ws;
  size_t o = 0;
  unsigned short* h1b = (unsigned short*)(w + o); o += algn((size_t)NNODE * 256 * 2);
  unsigned short* W1bT = (unsigned short*)(w + o); o += algn((size_t)256 * 128 * 2);
  float* als1 = (float*)(w + o); o += algn((size_t)NNODE * 4 * 4);
  float* ald1 = (float*)(w + o); o += algn((size_t)NNODE * 4 * 4);
  int*   deg  = (int*)(w + o);   o += algn((size_t)NNODE * 4);
  int*   rowp = (int*)(w + o);   o += algn((size_t)(NNODE + 1) * 4);
  int*   rank = (int*)(w + o);   o += algn((size_t)NTOT * 4);
  int*   esrc = (int*)(w + o);   o += algn((size_t)NTOT * 4);
  int*   bsum = (int*)(w + o);   o += 256;
  float4* h2c = (float4*)(w + o); o += algn((size_t)NNODE * 16);
  (void)ws_size; (void)n_in; (void)in_sizes; (void)out_size;

  k_prep<<<dim3(32 + 196), dim3(256), 0, stream>>>(W1, W1bT, deg);
  k_gemm_deg<<<dim3(NGEMM + (NTOT + 255) / 256), dim3(256), 0, stream>>>(
      x, W1bT, a_s1, a_d1, h1b, als1, ald1, ei, deg, rank);
  k_scan1<<<dim3(NB_SCAN), dim3(1024), 0, stream>>>(deg, rowp, bsum);
  k_scan23<<<dim3((NNODE + 255) / 256), dim3(256), 0, stream>>>(rowp, bsum);
  k_scatter<<<dim3((NTOT + 255) / 256), dim3(256), 0, stream>>>(ei, rowp, rank, esrc);
  k_agg1<<<dim3(12500), dim3(256), 0, stream>>>(h1b, als1, ald1, rowp, esrc, b1,
                                                W2, a_s2, a_d2, h2c);
  k_agg2<<<dim3((NNODE + 255) / 256), dim3(256), 0, stream>>>(h2c, rowp, esrc, b2, out);
}

// Round 8
// 232.779 us; speedup vs baseline: 5.5219x; 1.0782x over previous
//
#include <hip/hip_runtime.h>

#define NNODE 50000
#define NEDGE 800000
#define NTOT  (NEDGE + NNODE)   // 850000 edges incl. self loops
#define NB_SCAN 49              // ceil(50000/1024)
#define NGEMM 1564              // 782 row-blocks x 2 col-halves

typedef __attribute__((ext_vector_type(8))) short bf16x8;
typedef __attribute__((ext_vector_type(4))) float f32x4;
union U4B8 { uint4 u; bf16x8 b; };

// ---- bf16 helpers (storage-only; all math in fp32) ----
__device__ __forceinline__ unsigned short f2bf(float f) {
  union { float f; unsigned u; } v; v.f = f;
  unsigned r = v.u + 0x7FFFu + ((v.u >> 16) & 1u);   // RN-even
  return (unsigned short)(r >> 16);
}
__device__ __forceinline__ float bflo(unsigned u) {
  union { unsigned u; float f; } v; v.u = u << 16; return v.f;
}
__device__ __forceinline__ float bfhi(unsigned u) {
  union { unsigned u; float f; } v; v.u = u & 0xFFFF0000u; return v.f;
}
__device__ __forceinline__ unsigned packbf(float a, float b) {
  return (unsigned)f2bf(a) | ((unsigned)f2bf(b) << 16);
}

// ---- prep: W1 -> bf16 transposed [256 cols][128 k] ----
__global__ __launch_bounds__(256) void k_prep(const float* __restrict__ W1,
                                              unsigned short* __restrict__ W1bT) {
  int flat = (int)blockIdx.x * 256 + threadIdx.x;   // 8192 total
  int k = flat >> 6, c4 = (flat & 63) << 2;
  float4 v = *(const float4*)(W1 + k * 256 + c4);
  W1bT[(c4 + 0) * 128 + k] = f2bf(v.x);
  W1bT[(c4 + 1) * 128 + k] = f2bf(v.y);
  W1bT[(c4 + 2) * 128 + k] = f2bf(v.z);
  W1bT[(c4 + 3) * 128 + k] = f2bf(v.w);
}

// ---- fused: MFMA GEMM (blocks < NGEMM) + degree histogram (+rank) --------
__global__ __launch_bounds__(256) void k_gemm_deg(
    const float* __restrict__ x, const unsigned short* __restrict__ W1bT,
    const float* __restrict__ a_s1, const float* __restrict__ a_d1,
    unsigned short* __restrict__ h1b, float* __restrict__ als1,
    float* __restrict__ ald1, const int* __restrict__ ei,
    int* __restrict__ deg, int* __restrict__ rank) {
  __shared__ unsigned short xs[64 * 136];
  if ((int)blockIdx.x >= NGEMM) {
    int i = ((int)blockIdx.x - NGEMM) * 256 + threadIdx.x;
    if (i < NTOT) {
      int d = (i < NEDGE) ? ei[NEDGE + i] : (i - NEDGE);
      rank[i] = atomicAdd(deg + d, 1);   // rank within dst bucket
    }
    return;
  }
  const int t = threadIdx.x;
  const int rb = (int)blockIdx.x >> 1, nhalf = (int)blockIdx.x & 1;
  const int grow0 = rb * 64;
#pragma unroll
  for (int i = 0; i < 8; ++i) {
    int f = t + i * 256;
    int row = f >> 5, c4 = (f & 31) << 2;
    int gr = grow0 + row;
    float4 v = make_float4(0.f, 0.f, 0.f, 0.f);
    if (gr < NNODE) v = *(const float4*)(x + gr * 128 + c4);
    *(uint2*)(xs + row * 136 + c4) = make_uint2(packbf(v.x, v.y), packbf(v.z, v.w));
  }
  const int wid = t >> 6, lane = t & 63;
  const int wrow = (wid >> 1) * 32;
  const int head = nhalf * 2 + (wid & 1);
  const int c_lo = lane & 15, g = lane >> 4;
  U4B8 bfr[4][4];
#pragma unroll
  for (int nr = 0; nr < 4; ++nr) {
    int c = head * 64 + nr * 16 + c_lo;
#pragma unroll
    for (int ks = 0; ks < 4; ++ks)
      bfr[nr][ks].u = *(const uint4*)(W1bT + c * 128 + ks * 32 + g * 8);
  }
  __syncthreads();
  U4B8 afr[2][4];
#pragma unroll
  for (int mr = 0; mr < 2; ++mr)
#pragma unroll
    for (int ks = 0; ks < 4; ++ks)
      afr[mr][ks].u = *(const uint4*)(xs + (wrow + mr * 16 + c_lo) * 136 + ks * 32 + g * 8);
  f32x4 acc[2][4];
#pragma unroll
  for (int mr = 0; mr < 2; ++mr)
#pragma unroll
    for (int nr = 0; nr < 4; ++nr) acc[mr][nr] = (f32x4){0.f, 0.f, 0.f, 0.f};
#pragma unroll
  for (int ks = 0; ks < 4; ++ks)
#pragma unroll
    for (int mr = 0; mr < 2; ++mr)
#pragma unroll
      for (int nr = 0; nr < 4; ++nr)
        acc[mr][nr] = __builtin_amdgcn_mfma_f32_16x16x32_bf16(
            afr[mr][ks].b, bfr[nr][ks].b, acc[mr][nr], 0, 0, 0);
  float as_v[4], ad_v[4];
#pragma unroll
  for (int nr = 0; nr < 4; ++nr) {
    as_v[nr] = a_s1[head * 64 + nr * 16 + c_lo];
    ad_v[nr] = a_d1[head * 64 + nr * 16 + c_lo];
  }
  float ps[2][4], pd[2][4];
#pragma unroll
  for (int mr = 0; mr < 2; ++mr)
#pragma unroll
    for (int r = 0; r < 4; ++r) {
      float s = 0.f, dsum = 0.f;
#pragma unroll
      for (int nr = 0; nr < 4; ++nr) {
        s += acc[mr][nr][r] * as_v[nr];
        dsum += acc[mr][nr][r] * ad_v[nr];
      }
      ps[mr][r] = s; pd[mr][r] = dsum;
    }
#pragma unroll
  for (int m = 1; m < 16; m <<= 1)
#pragma unroll
    for (int mr = 0; mr < 2; ++mr)
#pragma unroll
      for (int r = 0; r < 4; ++r) {
        ps[mr][r] += __shfl_xor(ps[mr][r], m, 64);
        pd[mr][r] += __shfl_xor(pd[mr][r], m, 64);
      }
  if (c_lo == 0) {
#pragma unroll
    for (int mr = 0; mr < 2; ++mr)
#pragma unroll
      for (int r = 0; r < 4; ++r) {
        int node = grow0 + wrow + mr * 16 + g * 4 + r;
        if (node < NNODE) {
          als1[node * 4 + head] = ps[mr][r];
          ald1[node * 4 + head] = pd[mr][r];
        }
      }
  }
  __syncthreads();
  unsigned short* tb = xs + wid * 2048;
#pragma unroll
  for (int mr = 0; mr < 2; ++mr)
#pragma unroll
    for (int nr = 0; nr < 4; ++nr)
#pragma unroll
      for (int r = 0; r < 4; ++r)
        tb[(mr * 16 + g * 4 + r) * 64 + nr * 16 + c_lo] = f2bf(acc[mr][nr][r]);
#pragma unroll
  for (int i = 0; i < 4; ++i) {
    int unit = i * 64 + lane;
    int row = unit >> 3, cS = (unit & 7) * 8;
    int node = grow0 + wrow + row;
    if (node < NNODE) {
      uint4 v = *(const uint4*)(tb + unit * 8);
      *(uint4*)(h1b + (size_t)node * 256 + nhalf * 128 + (wid & 1) * 64 + cS) = v;
    }
  }
}

// ---------------- CSR scan ----------------
__global__ __launch_bounds__(1024) void k_scan1(const int* __restrict__ deg,
                                                int* __restrict__ rowptr,
                                                int* __restrict__ bsum) {
  __shared__ int sh[1024];
  const int t = threadIdx.x;
  const int idx = (int)blockIdx.x * 1024 + t;
  int v = (idx < NNODE) ? deg[idx] : 0;
  sh[t] = v;
  __syncthreads();
#pragma unroll
  for (int off = 1; off < 1024; off <<= 1) {
    int add = (t >= off) ? sh[t - off] : 0;
    __syncthreads();
    sh[t] += add;
    __syncthreads();
  }
  if (idx < NNODE) rowptr[idx + 1] = sh[t];
  if (t == 1023) bsum[blockIdx.x] = sh[1023];
}

// block-local wave scan of the 49 block sums; finalize rowptr
__global__ __launch_bounds__(256) void k_scan23(int* __restrict__ rowptr,
                                                const int* __restrict__ bsum) {
  __shared__ int boff[64];
  const int t = threadIdx.x;
  if (t < 64) {
    int v = (t < NB_SCAN) ? bsum[t] : 0;
    int orig = v;
#pragma unroll
    for (int off = 1; off < 64; off <<= 1) {
      int n = __shfl_up(v, off, 64);
      if (t >= off) v += n;
    }
    boff[t] = v - orig;   // exclusive prefix
  }
  __syncthreads();
  int idx = (int)blockIdx.x * 256 + t;
  if (idx < NNODE) {
    rowptr[idx + 1] += boff[idx >> 10];
    if (idx == 0) rowptr[0] = 0;
  }
}

// ---- scatter, atomic-free: pos = rowptr[d] + rank[i] ----
__global__ void k_scatter(const int* __restrict__ ei,
                          const int* __restrict__ rowptr,
                          const int* __restrict__ rank,
                          int* __restrict__ esrc) {
  int i = (int)blockIdx.x * blockDim.x + threadIdx.x;
  if (i >= NTOT) return;
  int s, d;
  if (i < NEDGE) { s = ei[i]; d = ei[NEDGE + i]; }
  else           { s = i - NEDGE; d = s; }
  esrc[rowptr[d] + rank[i]] = s;
}

// ------- layer-1 aggregate + bias + relu + layer-2 linear/logits -------
// one wave per dst node; half-wave per edge (2 chains), 1-deep esrc prefetch.
__global__ __launch_bounds__(256) void k_agg1(
    const unsigned short* __restrict__ h1b, const float* __restrict__ als1,
    const float* __restrict__ ald1, const int* __restrict__ rowptr,
    const int* __restrict__ esrc, const float* __restrict__ b1,
    const float* __restrict__ W2, const float* __restrict__ a_s2,
    const float* __restrict__ a_d2, float4* __restrict__ h2c) {
  const int w = threadIdx.x >> 6, lane = threadIdx.x & 63;
  const int d = (int)blockIdx.x * 4 + w;           // grid = 12500
  const int half = lane >> 5, cl = lane & 31;
  const int head = cl >> 3;
  const float ald = ald1[d * 4 + head];
  const int begin = rowptr[d], end = rowptr[d + 1];
  float acc[8];
#pragma unroll
  for (int i = 0; i < 8; ++i) acc[i] = 0.f;
  float S = 0.f;

  int j = begin + half;
  int s = (j < end) ? esrc[j] : -1;
  while (s >= 0) {
    const uint4 hv = *(const uint4*)(h1b + (size_t)s * 256 + cl * 8);
    float e = als1[s * 4 + head] + ald;
    int jn = j + 2;
    int sn = (jn < end) ? esrc[jn] : -1;
    e = fmaxf(e, 0.2f * e);               // leaky relu
    float wgt = __expf(e);
    S += wgt;
    acc[0] += wgt * bflo(hv.x); acc[1] += wgt * bfhi(hv.x);
    acc[2] += wgt * bflo(hv.y); acc[3] += wgt * bfhi(hv.y);
    acc[4] += wgt * bflo(hv.z); acc[5] += wgt * bfhi(hv.z);
    acc[6] += wgt * bflo(hv.w); acc[7] += wgt * bfhi(hv.w);
    j = jn; s = sn;
  }
  // combine the two half-waves
  S += __shfl_xor(S, 32, 64);
#pragma unroll
  for (int i = 0; i < 8; ++i) acc[i] += __shfl_xor(acc[i], 32, 64);

  const float inv = 1.f / S;
  const int c0 = cl * 8;
  float4 ba = *(const float4*)(b1 + c0);
  float4 bb = *(const float4*)(b1 + c0 + 4);
  float bias[8] = {ba.x, ba.y, ba.z, ba.w, bb.x, bb.y, bb.z, bb.w};
  float4 w0 = *(const float4*)(W2 + c0 * 2);
  float4 w1 = *(const float4*)(W2 + c0 * 2 + 4);
  float4 w2 = *(const float4*)(W2 + c0 * 2 + 8);
  float4 w3 = *(const float4*)(W2 + c0 * 2 + 12);
  float wa[16] = {w0.x, w0.y, w0.z, w0.w, w1.x, w1.y, w1.z, w1.w,
                  w2.x, w2.y, w2.z, w2.w, w3.x, w3.y, w3.z, w3.w};
  float p0 = 0.f, p1 = 0.f;
#pragma unroll
  for (int i = 0; i < 8; ++i) {
    float v = acc[i] * inv + bias[i];
    v = v > 0.f ? v : 0.f;
    p0 += v * wa[2 * i];
    p1 += v * wa[2 * i + 1];
  }
#pragma unroll
  for (int m = 1; m < 32; m <<= 1) {
    p0 += __shfl_xor(p0, m, 64);
    p1 += __shfl_xor(p1, m, 64);
  }
  if (lane == 0) {
    h2c[d] = make_float4(p0, p1,
                         p0 * a_s2[0] + p1 * a_s2[1],
                         p0 * a_d2[0] + p1 * a_d2[1]);
  }
}

// ---------------- layer-2 aggregate -> out (thread per dst) ----------------
__global__ __launch_bounds__(256) void k_agg2(
    const float4* __restrict__ h2c, const int* __restrict__ rowptr,
    const int* __restrict__ esrc, const float* __restrict__ b2,
    float* __restrict__ out) {
  int d = (int)blockIdx.x * 256 + threadIdx.x;
  if (d >= NNODE) return;
  const float ald = h2c[d].w;
  const int begin = rowptr[d], end = rowptr[d + 1];
  float S = 0.f, a0 = 0.f, a1 = 0.f;
  for (int j = begin; j < end; ++j) {
    int s = esrc[j];
    float4 v = h2c[s];
    float e = v.z + ald;
    e = fmaxf(e, 0.2f * e);
    float wgt = __expf(e);
    S += wgt;
    a0 += wgt * v.x;
    a1 += wgt * v.y;
  }
  float inv = 1.f / S;
  out[d * 2 + 0] = a0 * inv + b2[0];
  out[d * 2 + 1] = a1 * inv + b2[1];
}

static inline size_t algn(size_t x) { return (x + 255) & ~(size_t)255; }

extern "C" void kernel_launch(void* const* d_in, const int* in_sizes, int n_in,
                              void* d_out, int out_size, void* d_ws, size_t ws_size,
                              hipStream_t stream) {
  const float* x    = (const float*)d_in[0];
  const int*   ei   = (const int*)d_in[1];
  const float* W1   = (const float*)d_in[2];
  const float* a_s1 = (const float*)d_in[3];
  const float* a_d1 = (const float*)d_in[4];
  const float* b1   = (const float*)d_in[5];
  const float* W2   = (const float*)d_in[6];
  const float* a_s2 = (const float*)d_in[7];
  const float* a_d2 = (const float*)d_in[8];
  const float* b2   = (const float*)d_in[9];
  float* out = (float*)d_out;

  char* w = (char*)d_ws;
  size_t o = 0;
  unsigned short* h1b = (unsigned short*)(w + o); o += algn((size_t)NNODE * 256 * 2);
  unsigned short* W1bT = (unsigned short*)(w + o); o += algn((size_t)256 * 128 * 2);
  float* als1 = (float*)(w + o); o += algn((size_t)NNODE * 4 * 4);
  float* ald1 = (float*)(w + o); o += algn((size_t)NNODE * 4 * 4);
  int*   deg  = (int*)(w + o);   o += algn((size_t)NNODE * 4);
  int*   rowp = (int*)(w + o);   o += algn((size_t)(NNODE + 1) * 4);
  int*   rank = (int*)(w + o);   o += algn((size_t)NTOT * 4);
  int*   esrc = (int*)(w + o);   o += algn((size_t)NTOT * 4);
  int*   bsum = (int*)(w + o);   o += 256;
  float4* h2c = (float4*)(w + o); o += algn((size_t)NNODE * 16);
  (void)ws_size; (void)n_in; (void)in_sizes; (void)out_size;

  hipMemsetAsync(deg, 0, (size_t)NNODE * 4, stream);
  k_prep<<<dim3(32), dim3(256), 0, stream>>>(W1, W1bT);
  k_gemm_deg<<<dim3(NGEMM + (NTOT + 255) / 256), dim3(256), 0, stream>>>(
      x, W1bT, a_s1, a_d1, h1b, als1, ald1, ei, deg, rank);
  k_scan1<<<dim3(NB_SCAN), dim3(1024), 0, stream>>>(deg, rowp, bsum);
  k_scan23<<<dim3((NNODE + 255) / 256), dim3(256), 0, stream>>>(rowp, bsum);
  k_scatter<<<dim3((NTOT + 255) / 256), dim3(256), 0, stream>>>(ei, rowp, rank, esrc);
  k_agg1<<<dim3(12500), dim3(256), 0, stream>>>(h1b, als1, ald1, rowp, esrc, b1,
                                                W2, a_s2, a_d2, h2c);
  k_agg2<<<dim3((NNODE + 255) / 256), dim3(256), 0, stream>>>(h2c, rowp, esrc, b2, out);
}

// Round 9
// 227.875 us; speedup vs baseline: 5.6408x; 1.0215x over previous
//
#include <hip/hip_runtime.h>

#define NNODE 50000
#define NEDGE 800000
#define NTOT  (NEDGE + NNODE)   // 850000 edges incl. self loops
#define NB_SCAN 49              // ceil(50000/1024)
#define NGEMM 1564              // 782 row-blocks x 2 col-halves

typedef __attribute__((ext_vector_type(8))) short bf16x8;
typedef __attribute__((ext_vector_type(4))) float f32x4;
union U4B8 { uint4 u; bf16x8 b; };

// ---- bf16 helpers (storage-only; all math in fp32) ----
__device__ __forceinline__ unsigned short f2bf(float f) {
  union { float f; unsigned u; } v; v.f = f;
  unsigned r = v.u + 0x7FFFu + ((v.u >> 16) & 1u);   // RN-even
  return (unsigned short)(r >> 16);
}
__device__ __forceinline__ float bflo(unsigned u) {
  union { unsigned u; float f; } v; v.u = u << 16; return v.f;
}
__device__ __forceinline__ float bfhi(unsigned u) {
  union { unsigned u; float f; } v; v.u = u & 0xFFFF0000u; return v.f;
}
__device__ __forceinline__ unsigned packbf(float a, float b) {
  return (unsigned)f2bf(a) | ((unsigned)f2bf(b) << 16);
}

// ---- prep: W1 -> bf16 transposed [256][128] + zero deg (one dispatch) ----
__global__ __launch_bounds__(256) void k_prep(const float* __restrict__ W1,
                                              unsigned short* __restrict__ W1bT,
                                              int* __restrict__ deg) {
  const int b = (int)blockIdx.x;
  if (b < 32) {
    int flat = b * 256 + threadIdx.x;   // 8192 total
    int k = flat >> 6, c4 = (flat & 63) << 2;
    float4 v = *(const float4*)(W1 + k * 256 + c4);
    W1bT[(c4 + 0) * 128 + k] = f2bf(v.x);
    W1bT[(c4 + 1) * 128 + k] = f2bf(v.y);
    W1bT[(c4 + 2) * 128 + k] = f2bf(v.z);
    W1bT[(c4 + 3) * 128 + k] = f2bf(v.w);
  } else {
    int i = (b - 32) * 256 + threadIdx.x;
    if (i < NNODE) deg[i] = 0;
  }
}

// ---- fused: MFMA GEMM (blocks < NGEMM) + degree histogram (+rank) --------
__global__ __launch_bounds__(256) void k_gemm_deg(
    const float* __restrict__ x, const unsigned short* __restrict__ W1bT,
    const float* __restrict__ a_s1, const float* __restrict__ a_d1,
    unsigned short* __restrict__ h1b, float* __restrict__ als1,
    float* __restrict__ ald1, const int* __restrict__ ei,
    int* __restrict__ deg, int* __restrict__ rank) {
  __shared__ unsigned short xs[64 * 136];
  if ((int)blockIdx.x >= NGEMM) {
    int i = ((int)blockIdx.x - NGEMM) * 256 + threadIdx.x;
    if (i < NTOT) {
      int d = (i < NEDGE) ? ei[NEDGE + i] : (i - NEDGE);
      rank[i] = atomicAdd(deg + d, 1);   // rank within dst bucket
    }
    return;
  }
  const int t = threadIdx.x;
  const int rb = (int)blockIdx.x >> 1, nhalf = (int)blockIdx.x & 1;
  const int grow0 = rb * 64;
#pragma unroll
  for (int i = 0; i < 8; ++i) {
    int f = t + i * 256;
    int row = f >> 5, c4 = (f & 31) << 2;
    int gr = grow0 + row;
    float4 v = make_float4(0.f, 0.f, 0.f, 0.f);
    if (gr < NNODE) v = *(const float4*)(x + gr * 128 + c4);
    *(uint2*)(xs + row * 136 + c4) = make_uint2(packbf(v.x, v.y), packbf(v.z, v.w));
  }
  const int wid = t >> 6, lane = t & 63;
  const int wrow = (wid >> 1) * 32;
  const int head = nhalf * 2 + (wid & 1);
  const int c_lo = lane & 15, g = lane >> 4;
  U4B8 bfr[4][4];
#pragma unroll
  for (int nr = 0; nr < 4; ++nr) {
    int c = head * 64 + nr * 16 + c_lo;
#pragma unroll
    for (int ks = 0; ks < 4; ++ks)
      bfr[nr][ks].u = *(const uint4*)(W1bT + c * 128 + ks * 32 + g * 8);
  }
  __syncthreads();
  U4B8 afr[2][4];
#pragma unroll
  for (int mr = 0; mr < 2; ++mr)
#pragma unroll
    for (int ks = 0; ks < 4; ++ks)
      afr[mr][ks].u = *(const uint4*)(xs + (wrow + mr * 16 + c_lo) * 136 + ks * 32 + g * 8);
  f32x4 acc[2][4];
#pragma unroll
  for (int mr = 0; mr < 2; ++mr)
#pragma unroll
    for (int nr = 0; nr < 4; ++nr) acc[mr][nr] = (f32x4){0.f, 0.f, 0.f, 0.f};
#pragma unroll
  for (int ks = 0; ks < 4; ++ks)
#pragma unroll
    for (int mr = 0; mr < 2; ++mr)
#pragma unroll
      for (int nr = 0; nr < 4; ++nr)
        acc[mr][nr] = __builtin_amdgcn_mfma_f32_16x16x32_bf16(
            afr[mr][ks].b, bfr[nr][ks].b, acc[mr][nr], 0, 0, 0);
  float as_v[4], ad_v[4];
#pragma unroll
  for (int nr = 0; nr < 4; ++nr) {
    as_v[nr] = a_s1[head * 64 + nr * 16 + c_lo];
    ad_v[nr] = a_d1[head * 64 + nr * 16 + c_lo];
  }
  float ps[2][4], pd[2][4];
#pragma unroll
  for (int mr = 0; mr < 2; ++mr)
#pragma unroll
    for (int r = 0; r < 4; ++r) {
      float s = 0.f, dsum = 0.f;
#pragma unroll
      for (int nr = 0; nr < 4; ++nr) {
        s += acc[mr][nr][r] * as_v[nr];
        dsum += acc[mr][nr][r] * ad_v[nr];
      }
      ps[mr][r] = s; pd[mr][r] = dsum;
    }
#pragma unroll
  for (int m = 1; m < 16; m <<= 1)
#pragma unroll
    for (int mr = 0; mr < 2; ++mr)
#pragma unroll
      for (int r = 0; r < 4; ++r) {
        ps[mr][r] += __shfl_xor(ps[mr][r], m, 64);
        pd[mr][r] += __shfl_xor(pd[mr][r], m, 64);
      }
  if (c_lo == 0) {
#pragma unroll
    for (int mr = 0; mr < 2; ++mr)
#pragma unroll
      for (int r = 0; r < 4; ++r) {
        int node = grow0 + wrow + mr * 16 + g * 4 + r;
        if (node < NNODE) {
          als1[node * 4 + head] = ps[mr][r];
          ald1[node * 4 + head] = pd[mr][r];
        }
      }
  }
  __syncthreads();
  unsigned short* tb = xs + wid * 2048;
#pragma unroll
  for (int mr = 0; mr < 2; ++mr)
#pragma unroll
    for (int nr = 0; nr < 4; ++nr)
#pragma unroll
      for (int r = 0; r < 4; ++r)
        tb[(mr * 16 + g * 4 + r) * 64 + nr * 16 + c_lo] = f2bf(acc[mr][nr][r]);
#pragma unroll
  for (int i = 0; i < 4; ++i) {
    int unit = i * 64 + lane;
    int row = unit >> 3, cS = (unit & 7) * 8;
    int node = grow0 + wrow + row;
    if (node < NNODE) {
      uint4 v = *(const uint4*)(tb + unit * 8);
      *(uint4*)(h1b + (size_t)node * 256 + nhalf * 128 + (wid & 1) * 64 + cS) = v;
    }
  }
}

// ---------------- CSR scan (partial: per-1024-block inclusive) -------------
__global__ __launch_bounds__(1024) void k_scan1(const int* __restrict__ deg,
                                                int* __restrict__ rowp,
                                                int* __restrict__ bsum) {
  __shared__ int sh[1024];
  const int t = threadIdx.x;
  const int idx = (int)blockIdx.x * 1024 + t;
  int v = (idx < NNODE) ? deg[idx] : 0;
  sh[t] = v;
  __syncthreads();
#pragma unroll
  for (int off = 1; off < 1024; off <<= 1) {
    int add = (t >= off) ? sh[t - off] : 0;
    __syncthreads();
    sh[t] += add;
    __syncthreads();
  }
  if (idx < NNODE) rowp[idx + 1] = sh[t];
  if (t == 1023) bsum[blockIdx.x] = sh[1023];
}

// ---- fused scan-finalize + scatter: every block redundantly scans bsum ----
// writes finalized rowptr to rowf (separate array -> no cross-block race),
// scatters edges via partial rowp + boff + rank.
__global__ __launch_bounds__(256) void k_scanscatter(
    const int* __restrict__ ei, const int* __restrict__ rowp,
    const int* __restrict__ bsum, const int* __restrict__ rank,
    int* __restrict__ rowf, int* __restrict__ esrc) {
  __shared__ int boff[64];
  const int t = threadIdx.x;
  if (t < 64) {
    int v = (t < NB_SCAN) ? bsum[t] : 0;
    int orig = v;
#pragma unroll
    for (int off = 1; off < 64; off <<= 1) {
      int n = __shfl_up(v, off, 64);
      if (t >= off) v += n;
    }
    boff[t] = v - orig;   // exclusive prefix of block sums
  }
  __syncthreads();
  const int i = (int)blockIdx.x * 256 + t;
  if (i < NNODE) {
    rowf[i + 1] = rowp[i + 1] + boff[i >> 10];
    if (i == 0) rowf[0] = 0;
  }
  if (i < NTOT) {
    int s, d;
    if (i < NEDGE) { s = ei[i]; d = ei[NEDGE + i]; }
    else           { s = i - NEDGE; d = s; }
    int base = (d == 0) ? 0 : rowp[d] + boff[(d - 1) >> 10];
    esrc[base + rank[i]] = s;
  }
}

// ------- layer-1 aggregate + bias + relu + layer-2 linear/logits -------
// one wave per dst node; half-wave per edge (2 chains), 1-deep esrc prefetch.
__global__ __launch_bounds__(256) void k_agg1(
    const unsigned short* __restrict__ h1b, const float* __restrict__ als1,
    const float* __restrict__ ald1, const int* __restrict__ rowptr,
    const int* __restrict__ esrc, const float* __restrict__ b1,
    const float* __restrict__ W2, const float* __restrict__ a_s2,
    const float* __restrict__ a_d2, float4* __restrict__ h2c) {
  const int w = threadIdx.x >> 6, lane = threadIdx.x & 63;
  const int d = (int)blockIdx.x * 4 + w;           // grid = 12500
  const int half = lane >> 5, cl = lane & 31;
  const int head = cl >> 3;
  const float ald = ald1[d * 4 + head];
  const int begin = rowptr[d], end = rowptr[d + 1];
  float acc[8];
#pragma unroll
  for (int i = 0; i < 8; ++i) acc[i] = 0.f;
  float S = 0.f;

  int j = begin + half;
  int s = (j < end) ? esrc[j] : -1;
  while (s >= 0) {
    const uint4 hv = *(const uint4*)(h1b + (size_t)s * 256 + cl * 8);
    float e = als1[s * 4 + head] + ald;
    int jn = j + 2;
    int sn = (jn < end) ? esrc[jn] : -1;
    e = fmaxf(e, 0.2f * e);               // leaky relu
    float wgt = __expf(e);
    S += wgt;
    acc[0] += wgt * bflo(hv.x); acc[1] += wgt * bfhi(hv.x);
    acc[2] += wgt * bflo(hv.y); acc[3] += wgt * bfhi(hv.y);
    acc[4] += wgt * bflo(hv.z); acc[5] += wgt * bfhi(hv.z);
    acc[6] += wgt * bflo(hv.w); acc[7] += wgt * bfhi(hv.w);
    j = jn; s = sn;
  }
  // combine the two half-waves
  S += __shfl_xor(S, 32, 64);
#pragma unroll
  for (int i = 0; i < 8; ++i) acc[i] += __shfl_xor(acc[i], 32, 64);

  const float inv = 1.f / S;
  const int c0 = cl * 8;
  float4 ba = *(const float4*)(b1 + c0);
  float4 bb = *(const float4*)(b1 + c0 + 4);
  float bias[8] = {ba.x, ba.y, ba.z, ba.w, bb.x, bb.y, bb.z, bb.w};
  float4 w0 = *(const float4*)(W2 + c0 * 2);
  float4 w1 = *(const float4*)(W2 + c0 * 2 + 4);
  float4 w2 = *(const float4*)(W2 + c0 * 2 + 8);
  float4 w3 = *(const float4*)(W2 + c0 * 2 + 12);
  float wa[16] = {w0.x, w0.y, w0.z, w0.w, w1.x, w1.y, w1.z, w1.w,
                  w2.x, w2.y, w2.z, w2.w, w3.x, w3.y, w3.z, w3.w};
  float p0 = 0.f, p1 = 0.f;
#pragma unroll
  for (int i = 0; i < 8; ++i) {
    float v = acc[i] * inv + bias[i];
    v = v > 0.f ? v : 0.f;
    p0 += v * wa[2 * i];
    p1 += v * wa[2 * i + 1];
  }
#pragma unroll
  for (int m = 1; m < 32; m <<= 1) {
    p0 += __shfl_xor(p0, m, 64);
    p1 += __shfl_xor(p1, m, 64);
  }
  if (lane == 0) {
    h2c[d] = make_float4(p0, p1,
                         p0 * a_s2[0] + p1 * a_s2[1],
                         p0 * a_d2[0] + p1 * a_d2[1]);
  }
}

// ---------------- layer-2 aggregate -> out (thread per dst) ----------------
__global__ __launch_bounds__(256) void k_agg2(
    const float4* __restrict__ h2c, const int* __restrict__ rowptr,
    const int* __restrict__ esrc, const float* __restrict__ b2,
    float* __restrict__ out) {
  int d = (int)blockIdx.x * 256 + threadIdx.x;
  if (d >= NNODE) return;
  const float ald = h2c[d].w;
  const int begin = rowptr[d], end = rowptr[d + 1];
  float S = 0.f, a0 = 0.f, a1 = 0.f;
  for (int j = begin; j < end; ++j) {
    int s = esrc[j];
    float4 v = h2c[s];
    float e = v.z + ald;
    e = fmaxf(e, 0.2f * e);
    float wgt = __expf(e);
    S += wgt;
    a0 += wgt * v.x;
    a1 += wgt * v.y;
  }
  float inv = 1.f / S;
  out[d * 2 + 0] = a0 * inv + b2[0];
  out[d * 2 + 1] = a1 * inv + b2[1];
}

static inline size_t algn(size_t x) { return (x + 255) & ~(size_t)255; }

extern "C" void kernel_launch(void* const* d_in, const int* in_sizes, int n_in,
                              void* d_out, int out_size, void* d_ws, size_t ws_size,
                              hipStream_t stream) {
  const float* x    = (const float*)d_in[0];
  const int*   ei   = (const int*)d_in[1];
  const float* W1   = (const float*)d_in[2];
  const float* a_s1 = (const float*)d_in[3];
  const float* a_d1 = (const float*)d_in[4];
  const float* b1   = (const float*)d_in[5];
  const float* W2   = (const float*)d_in[6];
  const float* a_s2 = (const float*)d_in[7];
  const float* a_d2 = (const float*)d_in[8];
  const float* b2   = (const float*)d_in[9];
  float* out = (float*)d_out;

  char* w = (char*)d_ws;
  size_t o = 0;
  unsigned short* h1b = (unsigned short*)(w + o); o += algn((size_t)NNODE * 256 * 2);
  unsigned short* W1bT = (unsigned short*)(w + o); o += algn((size_t)256 * 128 * 2);
  float* als1 = (float*)(w + o); o += algn((size_t)NNODE * 4 * 4);
  float* ald1 = (float*)(w + o); o += algn((size_t)NNODE * 4 * 4);
  int*   deg  = (int*)(w + o);   o += algn((size_t)NNODE * 4);
  int*   rowp = (int*)(w + o);   o += algn((size_t)(NNODE + 1) * 4);
  int*   rowf = (int*)(w + o);   o += algn((size_t)(NNODE + 1) * 4);
  int*   rank = (int*)(w + o);   o += algn((size_t)NTOT * 4);
  int*   esrc = (int*)(w + o);   o += algn((size_t)NTOT * 4);
  int*   bsum = (int*)(w + o);   o += 256;
  float4* h2c = (float4*)(w + o); o += algn((size_t)NNODE * 16);
  (void)ws_size; (void)n_in; (void)in_sizes; (void)out_size;

  k_prep<<<dim3(32 + 196), dim3(256), 0, stream>>>(W1, W1bT, deg);
  k_gemm_deg<<<dim3(NGEMM + (NTOT + 255) / 256), dim3(256), 0, stream>>>(
      x, W1bT, a_s1, a_d1, h1b, als1, ald1, ei, deg, rank);
  k_scan1<<<dim3(NB_SCAN), dim3(1024), 0, stream>>>(deg, rowp, bsum);
  k_scanscatter<<<dim3((NTOT + 255) / 256), dim3(256), 0, stream>>>(
      ei, rowp, bsum, rank, rowf, esrc);
  k_agg1<<<dim3(12500), dim3(256), 0, stream>>>(h1b, als1, ald1, rowf, esrc, b1,
                                                W2, a_s2, a_d2, h2c);
  k_agg2<<<dim3((NNODE + 255) / 256), dim3(256), 0, stream>>>(h2c, rowf, esrc, b2, out);
}

// Round 10
// 227.141 us; speedup vs baseline: 5.6590x; 1.0032x over previous
//
#include <hip/hip_runtime.h>

#define NNODE 50000
#define NEDGE 800000
#define NTOT  (NEDGE + NNODE)   // 850000 edges incl. self loops
#define NCHUNK 196              // ceil(50000/256)
#define NGEMM 782               // 64-row blocks (full 256-col)
#define NDEG 1661               // ceil(850000/512)

typedef __attribute__((ext_vector_type(8))) short bf16x8;
typedef __attribute__((ext_vector_type(4))) float f32x4;
union U4B8 { uint4 u; bf16x8 b; };

// ---- bf16 helpers (storage-only; all math in fp32) ----
__device__ __forceinline__ unsigned short f2bf(float f) {
  union { float f; unsigned u; } v; v.f = f;
  unsigned r = v.u + 0x7FFFu + ((v.u >> 16) & 1u);   // RN-even
  return (unsigned short)(r >> 16);
}
__device__ __forceinline__ float bflo(unsigned u) {
  union { unsigned u; float f; } v; v.u = u << 16; return v.f;
}
__device__ __forceinline__ float bfhi(unsigned u) {
  union { unsigned u; float f; } v; v.u = u & 0xFFFF0000u; return v.f;
}
__device__ __forceinline__ unsigned packbf(float a, float b) {
  return (unsigned)f2bf(a) | ((unsigned)f2bf(b) << 16);
}

// ---- prep: W1 -> bf16 transposed [256][128] + zero deg (one dispatch) ----
__global__ __launch_bounds__(256) void k_prep(const float* __restrict__ W1,
                                              unsigned short* __restrict__ W1bT,
                                              int* __restrict__ deg) {
  const int b = (int)blockIdx.x;
  if (b < 32) {
    int flat = b * 256 + threadIdx.x;   // 8192 total
    int k = flat >> 6, c4 = (flat & 63) << 2;
    float4 v = *(const float4*)(W1 + k * 256 + c4);
    W1bT[(c4 + 0) * 128 + k] = f2bf(v.x);
    W1bT[(c4 + 1) * 128 + k] = f2bf(v.y);
    W1bT[(c4 + 2) * 128 + k] = f2bf(v.z);
    W1bT[(c4 + 3) * 128 + k] = f2bf(v.w);
  } else {
    int i = (b - 32) * 256 + threadIdx.x;
    if (i < NNODE) deg[i] = 0;
  }
}

// ---- fused: MFMA GEMM 64x256 blocks (8 waves) + degree histogram (+rank) --
__global__ __launch_bounds__(512) void k_gemm_deg(
    const float* __restrict__ x, const unsigned short* __restrict__ W1bT,
    const float* __restrict__ a_s1, const float* __restrict__ a_d1,
    unsigned short* __restrict__ h1b, float* __restrict__ als1,
    float* __restrict__ ald1, const int* __restrict__ ei,
    int* __restrict__ deg, int* __restrict__ rank) {
  __shared__ unsigned short xs[16384];   // 32KB: A-tile (64x136) then scratch
  const int t = threadIdx.x;
  if ((int)blockIdx.x >= NGEMM) {
    int i = ((int)blockIdx.x - NGEMM) * 512 + t;
    if (i < NTOT) {
      int d = (i < NEDGE) ? ei[NEDGE + i] : (i - NEDGE);
      rank[i] = atomicAdd(deg + d, 1);   // rank within dst bucket
    }
    return;
  }
  const int grow0 = (int)blockIdx.x * 64;
  // stage A: 64x128 fp32 -> bf16 LDS (single read of x)
#pragma unroll
  for (int i = 0; i < 4; ++i) {
    int f = t + i * 512;
    int row = f >> 5, c4 = (f & 31) << 2;
    int gr = grow0 + row;
    float4 v = make_float4(0.f, 0.f, 0.f, 0.f);
    if (gr < NNODE) v = *(const float4*)(x + gr * 128 + c4);
    *(uint2*)(xs + row * 136 + c4) = make_uint2(packbf(v.x, v.y), packbf(v.z, v.w));
  }
  const int wid = t >> 6, lane = t & 63;
  const int wrow = (wid >> 2) * 32;           // row half
  const int head = wid & 3;                   // head slab (64 cols)
  const int c_lo = lane & 15, g = lane >> 4;
  U4B8 bfr[4][4];
#pragma unroll
  for (int nr = 0; nr < 4; ++nr) {
    int c = head * 64 + nr * 16 + c_lo;
#pragma unroll
    for (int ks = 0; ks < 4; ++ks)
      bfr[nr][ks].u = *(const uint4*)(W1bT + c * 128 + ks * 32 + g * 8);
  }
  __syncthreads();
  U4B8 afr[2][4];
#pragma unroll
  for (int mr = 0; mr < 2; ++mr)
#pragma unroll
    for (int ks = 0; ks < 4; ++ks)
      afr[mr][ks].u = *(const uint4*)(xs + (wrow + mr * 16 + c_lo) * 136 + ks * 32 + g * 8);
  f32x4 acc[2][4];
#pragma unroll
  for (int mr = 0; mr < 2; ++mr)
#pragma unroll
    for (int nr = 0; nr < 4; ++nr) acc[mr][nr] = (f32x4){0.f, 0.f, 0.f, 0.f};
#pragma unroll
  for (int ks = 0; ks < 4; ++ks)
#pragma unroll
    for (int mr = 0; mr < 2; ++mr)
#pragma unroll
      for (int nr = 0; nr < 4; ++nr)
        acc[mr][nr] = __builtin_amdgcn_mfma_f32_16x16x32_bf16(
            afr[mr][ks].b, bfr[nr][ks].b, acc[mr][nr], 0, 0, 0);
  // ---- attention-logit epilogue (full head dot within this wave) ----
  float as_v[4], ad_v[4];
#pragma unroll
  for (int nr = 0; nr < 4; ++nr) {
    as_v[nr] = a_s1[head * 64 + nr * 16 + c_lo];
    ad_v[nr] = a_d1[head * 64 + nr * 16 + c_lo];
  }
  float ps[2][4], pd[2][4];
#pragma unroll
  for (int mr = 0; mr < 2; ++mr)
#pragma unroll
    for (int r = 0; r < 4; ++r) {
      float s = 0.f, dsum = 0.f;
#pragma unroll
      for (int nr = 0; nr < 4; ++nr) {
        s += acc[mr][nr][r] * as_v[nr];
        dsum += acc[mr][nr][r] * ad_v[nr];
      }
      ps[mr][r] = s; pd[mr][r] = dsum;
    }
#pragma unroll
  for (int m = 1; m < 16; m <<= 1)
#pragma unroll
    for (int mr = 0; mr < 2; ++mr)
#pragma unroll
      for (int r = 0; r < 4; ++r) {
        ps[mr][r] += __shfl_xor(ps[mr][r], m, 64);
        pd[mr][r] += __shfl_xor(pd[mr][r], m, 64);
      }
  if (c_lo == 0) {
#pragma unroll
    for (int mr = 0; mr < 2; ++mr)
#pragma unroll
      for (int r = 0; r < 4; ++r) {
        int node = grow0 + wrow + mr * 16 + g * 4 + r;
        if (node < NNODE) {
          als1[node * 4 + head] = ps[mr][r];
          ald1[node * 4 + head] = pd[mr][r];
        }
      }
  }
  // ---- store h1b via wave-private LDS transpose ----
  __syncthreads();
  unsigned short* tb = xs + wid * 2048;   // 32x64 bf16 = 4KB per wave
#pragma unroll
  for (int mr = 0; mr < 2; ++mr)
#pragma unroll
    for (int nr = 0; nr < 4; ++nr)
#pragma unroll
      for (int r = 0; r < 4; ++r)
        tb[(mr * 16 + g * 4 + r) * 64 + nr * 16 + c_lo] = f2bf(acc[mr][nr][r]);
#pragma unroll
  for (int i = 0; i < 4; ++i) {
    int unit = i * 64 + lane;
    int row = unit >> 3, cS = (unit & 7) * 8;
    int node = grow0 + wrow + row;
    if (node < NNODE) {
      uint4 v = *(const uint4*)(tb + unit * 8);
      *(uint4*)(h1b + (size_t)node * 256 + head * 64 + cS) = v;
    }
  }
}

// ---- CSR scan: 256-node chunks, wave-shfl scan (196 blocks) ----
__global__ __launch_bounds__(256) void k_scan1(const int* __restrict__ deg,
                                               int* __restrict__ rowp,
                                               int* __restrict__ csum) {
  __shared__ int ws[4];
  const int t = threadIdx.x, lane = t & 63, wid = t >> 6;
  const int idx = (int)blockIdx.x * 256 + t;
  int sv = (idx < NNODE) ? deg[idx] : 0;
#pragma unroll
  for (int off = 1; off < 64; off <<= 1) {
    int n = __shfl_up(sv, off, 64);
    if (lane >= off) sv += n;
  }
  if (lane == 63) ws[wid] = sv;
  __syncthreads();
  int add = 0;
#pragma unroll
  for (int p = 0; p < 3; ++p) if (wid > p) add += ws[p];
  sv += add;
  if (idx < NNODE) rowp[idx + 1] = sv;
  if (t == 255) csum[blockIdx.x] = sv;
}

// ---- fused scan-finalize + scatter (every block redundantly scans csum) ---
__global__ __launch_bounds__(256) void k_scanscatter(
    const int* __restrict__ ei, const int* __restrict__ rowp,
    const int* __restrict__ csum, const int* __restrict__ rank,
    int* __restrict__ rowf, int* __restrict__ esrc) {
  __shared__ int boff[256];
  const int t = threadIdx.x;
  if (t < 64) {
    const int c0 = t * 4;
    int s0 = (c0 + 0 < NCHUNK) ? csum[c0 + 0] : 0;
    int s1 = (c0 + 1 < NCHUNK) ? csum[c0 + 1] : 0;
    int s2 = (c0 + 2 < NCHUNK) ? csum[c0 + 2] : 0;
    int s3 = (c0 + 3 < NCHUNK) ? csum[c0 + 3] : 0;
    int local = s0 + s1 + s2 + s3;
    int sv = local;
#pragma unroll
    for (int off = 1; off < 64; off <<= 1) {
      int n = __shfl_up(sv, off, 64);
      if (t >= off) sv += n;
    }
    int excl = sv - local;
    boff[c0 + 0] = excl;
    boff[c0 + 1] = excl + s0;
    boff[c0 + 2] = excl + s0 + s1;
    boff[c0 + 3] = excl + s0 + s1 + s2;
  }
  __syncthreads();
  const int i = (int)blockIdx.x * 256 + t;
  if (i < NNODE) {
    rowf[i + 1] = rowp[i + 1] + boff[i >> 8];
    if (i == 0) rowf[0] = 0;
  }
  if (i < NTOT) {
    int s, d;
    if (i < NEDGE) { s = ei[i]; d = ei[NEDGE + i]; }
    else           { s = i - NEDGE; d = s; }
    int base = (d == 0) ? 0 : rowp[d] + boff[(d - 1) >> 8];
    esrc[base + rank[i]] = s;
  }
}

// ------- layer-1 aggregate + bias + relu + layer-2 linear/logits -------
// one wave per dst node; half-wave per edge (2 chains), 1-deep esrc prefetch.
__global__ __launch_bounds__(256) void k_agg1(
    const unsigned short* __restrict__ h1b, const float* __restrict__ als1,
    const float* __restrict__ ald1, const int* __restrict__ rowptr,
    const int* __restrict__ esrc, const float* __restrict__ b1,
    const float* __restrict__ W2, const float* __restrict__ a_s2,
    const float* __restrict__ a_d2, float4* __restrict__ h2c) {
  const int w = threadIdx.x >> 6, lane = threadIdx.x & 63;
  const int d = (int)blockIdx.x * 4 + w;           // grid = 12500
  const int half = lane >> 5, cl = lane & 31;
  const int head = cl >> 3;
  const float ald = ald1[d * 4 + head];
  const int begin = rowptr[d], end = rowptr[d + 1];
  float acc[8];
#pragma unroll
  for (int i = 0; i < 8; ++i) acc[i] = 0.f;
  float S = 0.f;

  int j = begin + half;
  int s = (j < end) ? esrc[j] : -1;
  while (s >= 0) {
    const uint4 hv = *(const uint4*)(h1b + (size_t)s * 256 + cl * 8);
    float e = als1[s * 4 + head] + ald;
    int jn = j + 2;
    int sn = (jn < end) ? esrc[jn] : -1;
    e = fmaxf(e, 0.2f * e);               // leaky relu
    float wgt = __expf(e);
    S += wgt;
    acc[0] += wgt * bflo(hv.x); acc[1] += wgt * bfhi(hv.x);
    acc[2] += wgt * bflo(hv.y); acc[3] += wgt * bfhi(hv.y);
    acc[4] += wgt * bflo(hv.z); acc[5] += wgt * bfhi(hv.z);
    acc[6] += wgt * bflo(hv.w); acc[7] += wgt * bfhi(hv.w);
    j = jn; s = sn;
  }
  // combine the two half-waves
  S += __shfl_xor(S, 32, 64);
#pragma unroll
  for (int i = 0; i < 8; ++i) acc[i] += __shfl_xor(acc[i], 32, 64);

  const float inv = 1.f / S;
  const int c0 = cl * 8;
  float4 ba = *(const float4*)(b1 + c0);
  float4 bb = *(const float4*)(b1 + c0 + 4);
  float bias[8] = {ba.x, ba.y, ba.z, ba.w, bb.x, bb.y, bb.z, bb.w};
  float4 w0 = *(const float4*)(W2 + c0 * 2);
  float4 w1 = *(const float4*)(W2 + c0 * 2 + 4);
  float4 w2 = *(const float4*)(W2 + c0 * 2 + 8);
  float4 w3 = *(const float4*)(W2 + c0 * 2 + 12);
  float wa[16] = {w0.x, w0.y, w0.z, w0.w, w1.x, w1.y, w1.z, w1.w,
                  w2.x, w2.y, w2.z, w2.w, w3.x, w3.y, w3.z, w3.w};
  float p0 = 0.f, p1 = 0.f;
#pragma unroll
  for (int i = 0; i < 8; ++i) {
    float v = acc[i] * inv + bias[i];
    v = v > 0.f ? v : 0.f;
    p0 += v * wa[2 * i];
    p1 += v * wa[2 * i + 1];
  }
#pragma unroll
  for (int m = 1; m < 32; m <<= 1) {
    p0 += __shfl_xor(p0, m, 64);
    p1 += __shfl_xor(p1, m, 64);
  }
  if (lane == 0) {
    h2c[d] = make_float4(p0, p1,
                         p0 * a_s2[0] + p1 * a_s2[1],
                         p0 * a_d2[0] + p1 * a_d2[1]);
  }
}

// ------- layer-2 aggregate -> out (4 threads per dst, shfl combine) -------
__global__ __launch_bounds__(256) void k_agg2(
    const float4* __restrict__ h2c, const int* __restrict__ rowptr,
    const int* __restrict__ esrc, const float* __restrict__ b2,
    float* __restrict__ out) {
  const int t = threadIdx.x;
  const int g = t & 3;
  const int d = (int)blockIdx.x * 64 + (t >> 2);
  if (d >= NNODE) return;
  const float ald = h2c[d].w;
  const int begin = rowptr[d], end = rowptr[d + 1];
  float S = 0.f, a0 = 0.f, a1 = 0.f;
  for (int j = begin + g; j < end; j += 4) {
    int s = esrc[j];
    float4 v = h2c[s];
    float e = v.z + ald;
    e = fmaxf(e, 0.2f * e);
    float wgt = __expf(e);
    S += wgt;
    a0 += wgt * v.x;
    a1 += wgt * v.y;
  }
  S  += __shfl_xor(S, 1, 64);  S  += __shfl_xor(S, 2, 64);
  a0 += __shfl_xor(a0, 1, 64); a0 += __shfl_xor(a0, 2, 64);
  a1 += __shfl_xor(a1, 1, 64); a1 += __shfl_xor(a1, 2, 64);
  if (g == 0) {
    float inv = 1.f / S;
    out[d * 2 + 0] = a0 * inv + b2[0];
    out[d * 2 + 1] = a1 * inv + b2[1];
  }
}

static inline size_t algn(size_t x) { return (x + 255) & ~(size_t)255; }

extern "C" void kernel_launch(void* const* d_in, const int* in_sizes, int n_in,
                              void* d_out, int out_size, void* d_ws, size_t ws_size,
                              hipStream_t stream) {
  const float* x    = (const float*)d_in[0];
  const int*   ei   = (const int*)d_in[1];
  const float* W1   = (const float*)d_in[2];
  const float* a_s1 = (const float*)d_in[3];
  const float* a_d1 = (const float*)d_in[4];
  const float* b1   = (const float*)d_in[5];
  const float* W2   = (const float*)d_in[6];
  const float* a_s2 = (const float*)d_in[7];
  const float* a_d2 = (const float*)d_in[8];
  const float* b2   = (const float*)d_in[9];
  float* out = (float*)d_out;

  char* w = (char*)d_ws;
  size_t o = 0;
  unsigned short* h1b = (unsigned short*)(w + o); o += algn((size_t)NNODE * 256 * 2);
  unsigned short* W1bT = (unsigned short*)(w + o); o += algn((size_t)256 * 128 * 2);
  float* als1 = (float*)(w + o); o += algn((size_t)NNODE * 4 * 4);
  float* ald1 = (float*)(w + o); o += algn((size_t)NNODE * 4 * 4);
  int*   deg  = (int*)(w + o);   o += algn((size_t)NNODE * 4);
  int*   rowp = (int*)(w + o);   o += algn((size_t)(NNODE + 1) * 4);
  int*   rowf = (int*)(w + o);   o += algn((size_t)(NNODE + 1) * 4);
  int*   rank = (int*)(w + o);   o += algn((size_t)NTOT * 4);
  int*   esrc = (int*)(w + o);   o += algn((size_t)NTOT * 4);
  int*   csum = (int*)(w + o);   o += 1024;
  float4* h2c = (float4*)(w + o); o += algn((size_t)NNODE * 16);
  (void)ws_size; (void)n_in; (void)in_sizes; (void)out_size;

  k_prep<<<dim3(32 + 196), dim3(256), 0, stream>>>(W1, W1bT, deg);
  k_gemm_deg<<<dim3(NGEMM + NDEG), dim3(512), 0, stream>>>(
      x, W1bT, a_s1, a_d1, h1b, als1, ald1, ei, deg, rank);
  k_scan1<<<dim3(NCHUNK), dim3(256), 0, stream>>>(deg, rowp, csum);
  k_scanscatter<<<dim3((NTOT + 255) / 256), dim3(256), 0, stream>>>(
      ei, rowp, csum, rank, rowf, esrc);
  k_agg1<<<dim3(12500), dim3(256), 0, stream>>>(h1b, als1, ald1, rowf, esrc, b1,
                                                W2, a_s2, a_d2, h2c);
  k_agg2<<<dim3((NNODE + 63) / 64), dim3(256), 0, stream>>>(h2c, rowf, esrc, b2, out);
}

// Round 11
// 226.458 us; speedup vs baseline: 5.6761x; 1.0030x over previous
//
#include <hip/hip_runtime.h>

#define NNODE 50000
#define NEDGE 800000
#define NTOT  (NEDGE + NNODE)   // 850000 edges incl. self loops
#define NCHUNK 196              // ceil(50000/256)
#define NGEMM 1564              // 782 row-blocks x 2 col-halves

typedef __attribute__((ext_vector_type(8))) short bf16x8;
typedef __attribute__((ext_vector_type(4))) float f32x4;
union U4B8 { uint4 u; bf16x8 b; };

// ---- bf16 helpers (storage-only; all math in fp32) ----
__device__ __forceinline__ unsigned short f2bf(float f) {
  union { float f; unsigned u; } v; v.f = f;
  unsigned r = v.u + 0x7FFFu + ((v.u >> 16) & 1u);   // RN-even
  return (unsigned short)(r >> 16);
}
__device__ __forceinline__ float bflo(unsigned u) {
  union { unsigned u; float f; } v; v.u = u << 16; return v.f;
}
__device__ __forceinline__ float bfhi(unsigned u) {
  union { unsigned u; float f; } v; v.u = u & 0xFFFF0000u; return v.f;
}
__device__ __forceinline__ unsigned packbf(float a, float b) {
  return (unsigned)f2bf(a) | ((unsigned)f2bf(b) << 16);
}

// ---- prep: W1 -> bf16 transposed [256][128] + zero deg (one dispatch) ----
__global__ __launch_bounds__(256) void k_prep(const float* __restrict__ W1,
                                              unsigned short* __restrict__ W1bT,
                                              int* __restrict__ deg) {
  const int b = (int)blockIdx.x;
  if (b < 32) {
    int flat = b * 256 + threadIdx.x;   // 8192 total
    int k = flat >> 6, c4 = (flat & 63) << 2;
    float4 v = *(const float4*)(W1 + k * 256 + c4);
    W1bT[(c4 + 0) * 128 + k] = f2bf(v.x);
    W1bT[(c4 + 1) * 128 + k] = f2bf(v.y);
    W1bT[(c4 + 2) * 128 + k] = f2bf(v.z);
    W1bT[(c4 + 3) * 128 + k] = f2bf(v.w);
  } else {
    int i = (b - 32) * 256 + threadIdx.x;
    if (i < NNODE) deg[i] = 0;
  }
}

// ---- fused: MFMA GEMM (blocks < NGEMM, 64x128 col-half) + histogram ------
__global__ __launch_bounds__(256) void k_gemm_deg(
    const float* __restrict__ x, const unsigned short* __restrict__ W1bT,
    const float* __restrict__ a_s1, const float* __restrict__ a_d1,
    unsigned short* __restrict__ h1b, float* __restrict__ als1,
    float* __restrict__ ald1, const int* __restrict__ ei,
    int* __restrict__ deg, int* __restrict__ rank) {
  __shared__ unsigned short xs[64 * 136];   // 17408 B
  if ((int)blockIdx.x >= NGEMM) {
    int i = ((int)blockIdx.x - NGEMM) * 256 + threadIdx.x;
    if (i < NTOT) {
      int d = (i < NEDGE) ? ei[NEDGE + i] : (i - NEDGE);
      rank[i] = atomicAdd(deg + d, 1);   // rank within dst bucket
    }
    return;
  }
  const int t = threadIdx.x;
  const int rb = (int)blockIdx.x >> 1, nhalf = (int)blockIdx.x & 1;
  const int grow0 = rb * 64;
#pragma unroll
  for (int i = 0; i < 8; ++i) {
    int f = t + i * 256;
    int row = f >> 5, c4 = (f & 31) << 2;
    int gr = grow0 + row;
    float4 v = make_float4(0.f, 0.f, 0.f, 0.f);
    if (gr < NNODE) v = *(const float4*)(x + gr * 128 + c4);
    *(uint2*)(xs + row * 136 + c4) = make_uint2(packbf(v.x, v.y), packbf(v.z, v.w));
  }
  const int wid = t >> 6, lane = t & 63;
  const int wrow = (wid >> 1) * 32;
  const int head = nhalf * 2 + (wid & 1);
  const int c_lo = lane & 15, g = lane >> 4;
  U4B8 bfr[4][4];
#pragma unroll
  for (int nr = 0; nr < 4; ++nr) {
    int c = head * 64 + nr * 16 + c_lo;
#pragma unroll
    for (int ks = 0; ks < 4; ++ks)
      bfr[nr][ks].u = *(const uint4*)(W1bT + c * 128 + ks * 32 + g * 8);
  }
  __syncthreads();
  U4B8 afr[2][4];
#pragma unroll
  for (int mr = 0; mr < 2; ++mr)
#pragma unroll
    for (int ks = 0; ks < 4; ++ks)
      afr[mr][ks].u = *(const uint4*)(xs + (wrow + mr * 16 + c_lo) * 136 + ks * 32 + g * 8);
  f32x4 acc[2][4];
#pragma unroll
  for (int mr = 0; mr < 2; ++mr)
#pragma unroll
    for (int nr = 0; nr < 4; ++nr) acc[mr][nr] = (f32x4){0.f, 0.f, 0.f, 0.f};
#pragma unroll
  for (int ks = 0; ks < 4; ++ks)
#pragma unroll
    for (int mr = 0; mr < 2; ++mr)
#pragma unroll
      for (int nr = 0; nr < 4; ++nr)
        acc[mr][nr] = __builtin_amdgcn_mfma_f32_16x16x32_bf16(
            afr[mr][ks].b, bfr[nr][ks].b, acc[mr][nr], 0, 0, 0);
  float as_v[4], ad_v[4];
#pragma unroll
  for (int nr = 0; nr < 4; ++nr) {
    as_v[nr] = a_s1[head * 64 + nr * 16 + c_lo];
    ad_v[nr] = a_d1[head * 64 + nr * 16 + c_lo];
  }
  float ps[2][4], pd[2][4];
#pragma unroll
  for (int mr = 0; mr < 2; ++mr)
#pragma unroll
    for (int r = 0; r < 4; ++r) {
      float s = 0.f, dsum = 0.f;
#pragma unroll
      for (int nr = 0; nr < 4; ++nr) {
        s += acc[mr][nr][r] * as_v[nr];
        dsum += acc[mr][nr][r] * ad_v[nr];
      }
      ps[mr][r] = s; pd[mr][r] = dsum;
    }
#pragma unroll
  for (int m = 1; m < 16; m <<= 1)
#pragma unroll
    for (int mr = 0; mr < 2; ++mr)
#pragma unroll
      for (int r = 0; r < 4; ++r) {
        ps[mr][r] += __shfl_xor(ps[mr][r], m, 64);
        pd[mr][r] += __shfl_xor(pd[mr][r], m, 64);
      }
  if (c_lo == 0) {
#pragma unroll
    for (int mr = 0; mr < 2; ++mr)
#pragma unroll
      for (int r = 0; r < 4; ++r) {
        int node = grow0 + wrow + mr * 16 + g * 4 + r;
        if (node < NNODE) {
          als1[node * 4 + head] = ps[mr][r];
          ald1[node * 4 + head] = pd[mr][r];
        }
      }
  }
  // ---- store h1b via wave-private LDS transpose (stride 68: conflict-free)
  __syncthreads();
  unsigned short* tb = xs + wid * 2176;   // 32 x 68 shorts per wave
#pragma unroll
  for (int mr = 0; mr < 2; ++mr)
#pragma unroll
    for (int nr = 0; nr < 4; ++nr)
#pragma unroll
      for (int r = 0; r < 4; ++r)
        tb[(mr * 16 + g * 4 + r) * 68 + nr * 16 + c_lo] = f2bf(acc[mr][nr][r]);
#pragma unroll
  for (int i = 0; i < 4; ++i) {
    int unit = i * 64 + lane;
    int row = unit >> 3, cS = (unit & 7) * 8;
    int node = grow0 + wrow + row;
    if (node < NNODE) {
      uint4 v = *(const uint4*)(tb + row * 68 + cS);
      *(uint4*)(h1b + (size_t)node * 256 + nhalf * 128 + (wid & 1) * 64 + cS) = v;
    }
  }
}

// ---- CSR scan: 256-node chunks, wave-shfl scan (196 blocks) ----
__global__ __launch_bounds__(256) void k_scan1(const int* __restrict__ deg,
                                               int* __restrict__ rowp,
                                               int* __restrict__ csum) {
  __shared__ int ws[4];
  const int t = threadIdx.x, lane = t & 63, wid = t >> 6;
  const int idx = (int)blockIdx.x * 256 + t;
  int sv = (idx < NNODE) ? deg[idx] : 0;
#pragma unroll
  for (int off = 1; off < 64; off <<= 1) {
    int n = __shfl_up(sv, off, 64);
    if (lane >= off) sv += n;
  }
  if (lane == 63) ws[wid] = sv;
  __syncthreads();
  int add = 0;
#pragma unroll
  for (int p = 0; p < 3; ++p) if (wid > p) add += ws[p];
  sv += add;
  if (idx < NNODE) rowp[idx + 1] = sv;
  if (t == 255) csum[blockIdx.x] = sv;
}

// ---- fused scan-finalize + scatter (every block redundantly scans csum) ---
__global__ __launch_bounds__(256) void k_scanscatter(
    const int* __restrict__ ei, const int* __restrict__ rowp,
    const int* __restrict__ csum, const int* __restrict__ rank,
    int* __restrict__ rowf, int* __restrict__ esrc) {
  __shared__ int boff[256];
  const int t = threadIdx.x;
  if (t < 64) {
    const int c0 = t * 4;
    int s0 = (c0 + 0 < NCHUNK) ? csum[c0 + 0] : 0;
    int s1 = (c0 + 1 < NCHUNK) ? csum[c0 + 1] : 0;
    int s2 = (c0 + 2 < NCHUNK) ? csum[c0 + 2] : 0;
    int s3 = (c0 + 3 < NCHUNK) ? csum[c0 + 3] : 0;
    int local = s0 + s1 + s2 + s3;
    int sv = local;
#pragma unroll
    for (int off = 1; off < 64; off <<= 1) {
      int n = __shfl_up(sv, off, 64);
      if (t >= off) sv += n;
    }
    int excl = sv - local;
    boff[c0 + 0] = excl;
    boff[c0 + 1] = excl + s0;
    boff[c0 + 2] = excl + s0 + s1;
    boff[c0 + 3] = excl + s0 + s1 + s2;
  }
  __syncthreads();
  const int i = (int)blockIdx.x * 256 + t;
  if (i < NNODE) {
    rowf[i + 1] = rowp[i + 1] + boff[i >> 8];
    if (i == 0) rowf[0] = 0;
  }
  if (i < NTOT) {
    int s, d;
    if (i < NEDGE) { s = ei[i]; d = ei[NEDGE + i]; }
    else           { s = i - NEDGE; d = s; }
    int base = (d == 0) ? 0 : rowp[d] + boff[(d - 1) >> 8];
    esrc[base + rank[i]] = s;
  }
}

// ------- layer-1 aggregate + bias + relu + layer-2 linear/logits -------
// one wave per dst node; half-wave per edge (2 chains), 1-deep esrc prefetch.
__global__ __launch_bounds__(256) void k_agg1(
    const unsigned short* __restrict__ h1b, const float* __restrict__ als1,
    const float* __restrict__ ald1, const int* __restrict__ rowptr,
    const int* __restrict__ esrc, const float* __restrict__ b1,
    const float* __restrict__ W2, const float* __restrict__ a_s2,
    const float* __restrict__ a_d2, float4* __restrict__ h2c) {
  const int w = threadIdx.x >> 6, lane = threadIdx.x & 63;
  const int d = (int)blockIdx.x * 4 + w;           // grid = 12500
  const int half = lane >> 5, cl = lane & 31;
  const int head = cl >> 3;
  const float ald = ald1[d * 4 + head];
  const int begin = rowptr[d], end = rowptr[d + 1];
  float acc[8];
#pragma unroll
  for (int i = 0; i < 8; ++i) acc[i] = 0.f;
  float S = 0.f;

  int j = begin + half;
  int s = (j < end) ? esrc[j] : -1;
  while (s >= 0) {
    const uint4 hv = *(const uint4*)(h1b + (size_t)s * 256 + cl * 8);
    float e = als1[s * 4 + head] + ald;
    int jn = j + 2;
    int sn = (jn < end) ? esrc[jn] : -1;
    e = fmaxf(e, 0.2f * e);               // leaky relu
    float wgt = __expf(e);
    S += wgt;
    acc[0] += wgt * bflo(hv.x); acc[1] += wgt * bfhi(hv.x);
    acc[2] += wgt * bflo(hv.y); acc[3] += wgt * bfhi(hv.y);
    acc[4] += wgt * bflo(hv.z); acc[5] += wgt * bfhi(hv.z);
    acc[6] += wgt * bflo(hv.w); acc[7] += wgt * bfhi(hv.w);
    j = jn; s = sn;
  }
  // combine the two half-waves
  S += __shfl_xor(S, 32, 64);
#pragma unroll
  for (int i = 0; i < 8; ++i) acc[i] += __shfl_xor(acc[i], 32, 64);

  const float inv = 1.f / S;
  const int c0 = cl * 8;
  float4 ba = *(const float4*)(b1 + c0);
  float4 bb = *(const float4*)(b1 + c0 + 4);
  float bias[8] = {ba.x, ba.y, ba.z, ba.w, bb.x, bb.y, bb.z, bb.w};
  float4 w0 = *(const float4*)(W2 + c0 * 2);
  float4 w1 = *(const float4*)(W2 + c0 * 2 + 4);
  float4 w2 = *(const float4*)(W2 + c0 * 2 + 8);
  float4 w3 = *(const float4*)(W2 + c0 * 2 + 12);
  float wa[16] = {w0.x, w0.y, w0.z, w0.w, w1.x, w1.y, w1.z, w1.w,
                  w2.x, w2.y, w2.z, w2.w, w3.x, w3.y, w3.z, w3.w};
  float p0 = 0.f, p1 = 0.f;
#pragma unroll
  for (int i = 0; i < 8; ++i) {
    float v = acc[i] * inv + bias[i];
    v = v > 0.f ? v : 0.f;
    p0 += v * wa[2 * i];
    p1 += v * wa[2 * i + 1];
  }
#pragma unroll
  for (int m = 1; m < 32; m <<= 1) {
    p0 += __shfl_xor(p0, m, 64);
    p1 += __shfl_xor(p1, m, 64);
  }
  if (lane == 0) {
    h2c[d] = make_float4(p0, p1,
                         p0 * a_s2[0] + p1 * a_s2[1],
                         p0 * a_d2[0] + p1 * a_d2[1]);
  }
}

// ------- layer-2 aggregate -> out (4 threads per dst, shfl combine) -------
__global__ __launch_bounds__(256) void k_agg2(
    const float4* __restrict__ h2c, const int* __restrict__ rowptr,
    const int* __restrict__ esrc, const float* __restrict__ b2,
    float* __restrict__ out) {
  const int t = threadIdx.x;
  const int g = t & 3;
  const int d = (int)blockIdx.x * 64 + (t >> 2);
  if (d >= NNODE) return;
  const float ald = h2c[d].w;
  const int begin = rowptr[d], end = rowptr[d + 1];
  float S = 0.f, a0 = 0.f, a1 = 0.f;
  for (int j = begin + g; j < end; j += 4) {
    int s = esrc[j];
    float4 v = h2c[s];
    float e = v.z + ald;
    e = fmaxf(e, 0.2f * e);
    float wgt = __expf(e);
    S += wgt;
    a0 += wgt * v.x;
    a1 += wgt * v.y;
  }
  S  += __shfl_xor(S, 1, 64);  S  += __shfl_xor(S, 2, 64);
  a0 += __shfl_xor(a0, 1, 64); a0 += __shfl_xor(a0, 2, 64);
  a1 += __shfl_xor(a1, 1, 64); a1 += __shfl_xor(a1, 2, 64);
  if (g == 0) {
    float inv = 1.f / S;
    out[d * 2 + 0] = a0 * inv + b2[0];
    out[d * 2 + 1] = a1 * inv + b2[1];
  }
}

static inline size_t algn(size_t x) { return (x + 255) & ~(size_t)255; }

extern "C" void kernel_launch(void* const* d_in, const int* in_sizes, int n_in,
                              void* d_out, int out_size, void* d_ws, size_t ws_size,
                              hipStream_t stream) {
  const float* x    = (const float*)d_in[0];
  const int*   ei   = (const int*)d_in[1];
  const float* W1   = (const float*)d_in[2];
  const float* a_s1 = (const float*)d_in[3];
  const float* a_d1 = (const float*)d_in[4];
  const float* b1   = (const float*)d_in[5];
  const float* W2   = (const float*)d_in[6];
  const float* a_s2 = (const float*)d_in[7];
  const float* a_d2 = (const float*)d_in[8];
  const float* b2   = (const float*)d_in[9];
  float* out = (float*)d_out;

  char* w = (char*)d_ws;
  size_t o = 0;
  unsigned short* h1b = (unsigned short*)(w + o); o += algn((size_t)NNODE * 256 * 2);
  unsigned short* W1bT = (unsigned short*)(w + o); o += algn((size_t)256 * 128 * 2);
  float* als1 = (float*)(w + o); o += algn((size_t)NNODE * 4 * 4);
  float* ald1 = (float*)(w + o); o += algn((size_t)NNODE * 4 * 4);
  int*   deg  = (int*)(w + o);   o += algn((size_t)NNODE * 4);
  int*   rowp = (int*)(w + o);   o += algn((size_t)(NNODE + 1) * 4);
  int*   rowf = (int*)(w + o);   o += algn((size_t)(NNODE + 1) * 4);
  int*   rank = (int*)(w + o);   o += algn((size_t)NTOT * 4);
  int*   esrc = (int*)(w + o);   o += algn((size_t)NTOT * 4);
  int*   csum = (int*)(w + o);   o += 1024;
  float4* h2c = (float4*)(w + o); o += algn((size_t)NNODE * 16);
  (void)ws_size; (void)n_in; (void)in_sizes; (void)out_size;

  k_prep<<<dim3(32 + 196), dim3(256), 0, stream>>>(W1, W1bT, deg);
  k_gemm_deg<<<dim3(NGEMM + (NTOT + 255) / 256), dim3(256), 0, stream>>>(
      x, W1bT, a_s1, a_d1, h1b, als1, ald1, ei, deg, rank);
  k_scan1<<<dim3(NCHUNK), dim3(256), 0, stream>>>(deg, rowp, csum);
  k_scanscatter<<<dim3((NTOT + 255) / 256), dim3(256), 0, stream>>>(
      ei, rowp, csum, rank, rowf, esrc);
  k_agg1<<<dim3(12500), dim3(256), 0, stream>>>(h1b, als1, ald1, rowf, esrc, b1,
                                                W2, a_s2, a_d2, h2c);
  k_agg2<<<dim3((NNODE + 63) / 64), dim3(256), 0, stream>>>(h2c, rowf, esrc, b2, out);
}

// Round 12
// 217.473 us; speedup vs baseline: 5.9106x; 1.0413x over previous
//
#include <hip/hip_runtime.h>

#define NNODE 50000
#define NEDGE 800000
#define NTOT  (NEDGE + NNODE)   // 850000 edges incl. self loops
#define NCHUNK 196              // ceil(50000/256)
#define NGEMM 1564              // 782 row-blocks x 2 col-halves
#define NHIST 831               // ceil(850000/1024), 4 edges/thread
#define NB_FUSED 2493           // interleave: bid%3==2 -> hist, else gemm

typedef __attribute__((ext_vector_type(8))) short bf16x8;
typedef __attribute__((ext_vector_type(4))) float f32x4;
union U4B8 { uint4 u; bf16x8 b; };

// ---- bf16 helpers (storage-only; all math in fp32) ----
__device__ __forceinline__ unsigned short f2bf(float f) {
  union { float f; unsigned u; } v; v.f = f;
  unsigned r = v.u + 0x7FFFu + ((v.u >> 16) & 1u);   // RN-even
  return (unsigned short)(r >> 16);
}
__device__ __forceinline__ float bflo(unsigned u) {
  union { unsigned u; float f; } v; v.u = u << 16; return v.f;
}
__device__ __forceinline__ float bfhi(unsigned u) {
  union { unsigned u; float f; } v; v.u = u & 0xFFFF0000u; return v.f;
}
__device__ __forceinline__ unsigned packbf(float a, float b) {
  return (unsigned)f2bf(a) | ((unsigned)f2bf(b) << 16);
}

// ---- prep: W1 -> bf16 transposed [256][128] + zero deg (one dispatch) ----
__global__ __launch_bounds__(256) void k_prep(const float* __restrict__ W1,
                                              unsigned short* __restrict__ W1bT,
                                              int* __restrict__ deg) {
  const int b = (int)blockIdx.x;
  if (b < 32) {
    int flat = b * 256 + threadIdx.x;   // 8192 total
    int k = flat >> 6, c4 = (flat & 63) << 2;
    float4 v = *(const float4*)(W1 + k * 256 + c4);
    W1bT[(c4 + 0) * 128 + k] = f2bf(v.x);
    W1bT[(c4 + 1) * 128 + k] = f2bf(v.y);
    W1bT[(c4 + 2) * 128 + k] = f2bf(v.z);
    W1bT[(c4 + 3) * 128 + k] = f2bf(v.w);
  } else {
    int i = (b - 32) * 256 + threadIdx.x;
    if (i < NNODE) deg[i] = 0;
  }
}

// ---- fused MFMA GEMM + degree histogram, ROUND-ROBIN interleaved ---------
// bid%3==2: histogram block (1024 edges, 4 atomics in flight per thread)
// else:     GEMM block (64x128 col-half tile)
__global__ __launch_bounds__(256) void k_gemm_deg(
    const float* __restrict__ x, const unsigned short* __restrict__ W1bT,
    const float* __restrict__ a_s1, const float* __restrict__ a_d1,
    unsigned short* __restrict__ h1b, float* __restrict__ als1,
    float* __restrict__ ald1, const int* __restrict__ ei,
    int* __restrict__ deg, int* __restrict__ rank) {
  __shared__ unsigned short xs[64 * 136];   // 17408 B
  const int bid = (int)blockIdx.x;
  const int t = threadIdx.x;
  if (bid % 3 == 2) {
    // ---- histogram role: edges [h*1024, h*1024+1024), strided by 256 ----
    const int h = bid / 3;
    const int i0 = h * 1024 + t;
#pragma unroll
    for (int u = 0; u < 4; ++u) {
      int i = i0 + u * 256;
      if (i < NTOT) {
        int d = (i < NEDGE) ? ei[NEDGE + i] : (i - NEDGE);
        rank[i] = atomicAdd(deg + d, 1);   // rank within dst bucket
      }
    }
    return;
  }
  const int gid = bid - bid / 3;            // gemm block index
  if (gid >= NGEMM) return;
  const int rb = gid >> 1, nhalf = gid & 1;
  const int grow0 = rb * 64;
#pragma unroll
  for (int i = 0; i < 8; ++i) {
    int f = t + i * 256;
    int row = f >> 5, c4 = (f & 31) << 2;
    int gr = grow0 + row;
    float4 v = make_float4(0.f, 0.f, 0.f, 0.f);
    if (gr < NNODE) v = *(const float4*)(x + gr * 128 + c4);
    *(uint2*)(xs + row * 136 + c4) = make_uint2(packbf(v.x, v.y), packbf(v.z, v.w));
  }
  const int wid = t >> 6, lane = t & 63;
  const int wrow = (wid >> 1) * 32;
  const int head = nhalf * 2 + (wid & 1);
  const int c_lo = lane & 15, g = lane >> 4;
  U4B8 bfr[4][4];
#pragma unroll
  for (int nr = 0; nr < 4; ++nr) {
    int c = head * 64 + nr * 16 + c_lo;
#pragma unroll
    for (int ks = 0; ks < 4; ++ks)
      bfr[nr][ks].u = *(const uint4*)(W1bT + c * 128 + ks * 32 + g * 8);
  }
  __syncthreads();
  U4B8 afr[2][4];
#pragma unroll
  for (int mr = 0; mr < 2; ++mr)
#pragma unroll
    for (int ks = 0; ks < 4; ++ks)
      afr[mr][ks].u = *(const uint4*)(xs + (wrow + mr * 16 + c_lo) * 136 + ks * 32 + g * 8);
  f32x4 acc[2][4];
#pragma unroll
  for (int mr = 0; mr < 2; ++mr)
#pragma unroll
    for (int nr = 0; nr < 4; ++nr) acc[mr][nr] = (f32x4){0.f, 0.f, 0.f, 0.f};
#pragma unroll
  for (int ks = 0; ks < 4; ++ks)
#pragma unroll
    for (int mr = 0; mr < 2; ++mr)
#pragma unroll
      for (int nr = 0; nr < 4; ++nr)
        acc[mr][nr] = __builtin_amdgcn_mfma_f32_16x16x32_bf16(
            afr[mr][ks].b, bfr[nr][ks].b, acc[mr][nr], 0, 0, 0);
  float as_v[4], ad_v[4];
#pragma unroll
  for (int nr = 0; nr < 4; ++nr) {
    as_v[nr] = a_s1[head * 64 + nr * 16 + c_lo];
    ad_v[nr] = a_d1[head * 64 + nr * 16 + c_lo];
  }
  float ps[2][4], pd[2][4];
#pragma unroll
  for (int mr = 0; mr < 2; ++mr)
#pragma unroll
    for (int r = 0; r < 4; ++r) {
      float s = 0.f, dsum = 0.f;
#pragma unroll
      for (int nr = 0; nr < 4; ++nr) {
        s += acc[mr][nr][r] * as_v[nr];
        dsum += acc[mr][nr][r] * ad_v[nr];
      }
      ps[mr][r] = s; pd[mr][r] = dsum;
    }
#pragma unroll
  for (int m = 1; m < 16; m <<= 1)
#pragma unroll
    for (int mr = 0; mr < 2; ++mr)
#pragma unroll
      for (int r = 0; r < 4; ++r) {
        ps[mr][r] += __shfl_xor(ps[mr][r], m, 64);
        pd[mr][r] += __shfl_xor(pd[mr][r], m, 64);
      }
  if (c_lo == 0) {
#pragma unroll
    for (int mr = 0; mr < 2; ++mr)
#pragma unroll
      for (int r = 0; r < 4; ++r) {
        int node = grow0 + wrow + mr * 16 + g * 4 + r;
        if (node < NNODE) {
          als1[node * 4 + head] = ps[mr][r];
          ald1[node * 4 + head] = pd[mr][r];
        }
      }
  }
  __syncthreads();
  unsigned short* tb = xs + wid * 2176;   // 32 x 68 shorts per wave
#pragma unroll
  for (int mr = 0; mr < 2; ++mr)
#pragma unroll
    for (int nr = 0; nr < 4; ++nr)
#pragma unroll
      for (int r = 0; r < 4; ++r)
        tb[(mr * 16 + g * 4 + r) * 68 + nr * 16 + c_lo] = f2bf(acc[mr][nr][r]);
#pragma unroll
  for (int i = 0; i < 4; ++i) {
    int unit = i * 64 + lane;
    int row = unit >> 3, cS = (unit & 7) * 8;
    int node = grow0 + wrow + row;
    if (node < NNODE) {
      uint4 v = *(const uint4*)(tb + row * 68 + cS);
      *(uint4*)(h1b + (size_t)node * 256 + nhalf * 128 + (wid & 1) * 64 + cS) = v;
    }
  }
}

// ---- CSR scan: 256-node chunks, wave-shfl scan (196 blocks) ----
__global__ __launch_bounds__(256) void k_scan1(const int* __restrict__ deg,
                                               int* __restrict__ rowp,
                                               int* __restrict__ csum) {
  __shared__ int ws[4];
  const int t = threadIdx.x, lane = t & 63, wid = t >> 6;
  const int idx = (int)blockIdx.x * 256 + t;
  int sv = (idx < NNODE) ? deg[idx] : 0;
#pragma unroll
  for (int off = 1; off < 64; off <<= 1) {
    int n = __shfl_up(sv, off, 64);
    if (lane >= off) sv += n;
  }
  if (lane == 63) ws[wid] = sv;
  __syncthreads();
  int add = 0;
#pragma unroll
  for (int p = 0; p < 3; ++p) if (wid > p) add += ws[p];
  sv += add;
  if (idx < NNODE) rowp[idx + 1] = sv;
  if (t == 255) csum[blockIdx.x] = sv;
}

// ---- fused scan-finalize + scatter (every block redundantly scans csum) ---
__global__ __launch_bounds__(256) void k_scanscatter(
    const int* __restrict__ ei, const int* __restrict__ rowp,
    const int* __restrict__ csum, const int* __restrict__ rank,
    int* __restrict__ rowf, int* __restrict__ esrc) {
  __shared__ int boff[256];
  const int t = threadIdx.x;
  if (t < 64) {
    const int c0 = t * 4;
    int s0 = (c0 + 0 < NCHUNK) ? csum[c0 + 0] : 0;
    int s1 = (c0 + 1 < NCHUNK) ? csum[c0 + 1] : 0;
    int s2 = (c0 + 2 < NCHUNK) ? csum[c0 + 2] : 0;
    int s3 = (c0 + 3 < NCHUNK) ? csum[c0 + 3] : 0;
    int local = s0 + s1 + s2 + s3;
    int sv = local;
#pragma unroll
    for (int off = 1; off < 64; off <<= 1) {
      int n = __shfl_up(sv, off, 64);
      if (t >= off) sv += n;
    }
    int excl = sv - local;
    boff[c0 + 0] = excl;
    boff[c0 + 1] = excl + s0;
    boff[c0 + 2] = excl + s0 + s1;
    boff[c0 + 3] = excl + s0 + s1 + s2;
  }
  __syncthreads();
  const int i = (int)blockIdx.x * 256 + t;
  if (i < NNODE) {
    rowf[i + 1] = rowp[i + 1] + boff[i >> 8];
    if (i == 0) rowf[0] = 0;
  }
  if (i < NTOT) {
    int s, d;
    if (i < NEDGE) { s = ei[i]; d = ei[NEDGE + i]; }
    else           { s = i - NEDGE; d = s; }
    int base = (d == 0) ? 0 : rowp[d] + boff[(d - 1) >> 8];
    esrc[base + rank[i]] = s;
  }
}

// ------- layer-1 aggregate + bias + relu + layer-2 linear/logits -------
// one wave per dst node; half-wave per edge (2 chains), 1-deep esrc prefetch.
__global__ __launch_bounds__(256) void k_agg1(
    const unsigned short* __restrict__ h1b, const float* __restrict__ als1,
    const float* __restrict__ ald1, const int* __restrict__ rowptr,
    const int* __restrict__ esrc, const float* __restrict__ b1,
    const float* __restrict__ W2, const float* __restrict__ a_s2,
    const float* __restrict__ a_d2, float4* __restrict__ h2c) {
  const int w = threadIdx.x >> 6, lane = threadIdx.x & 63;
  const int d = (int)blockIdx.x * 4 + w;           // grid = 12500
  const int half = lane >> 5, cl = lane & 31;
  const int head = cl >> 3;
  const float ald = ald1[d * 4 + head];
  const int begin = rowptr[d], end = rowptr[d + 1];
  float acc[8];
#pragma unroll
  for (int i = 0; i < 8; ++i) acc[i] = 0.f;
  float S = 0.f;

  int j = begin + half;
  int s = (j < end) ? esrc[j] : -1;
  while (s >= 0) {
    const uint4 hv = *(const uint4*)(h1b + (size_t)s * 256 + cl * 8);
    float e = als1[s * 4 + head] + ald;
    int jn = j + 2;
    int sn = (jn < end) ? esrc[jn] : -1;
    e = fmaxf(e, 0.2f * e);               // leaky relu
    float wgt = __expf(e);
    S += wgt;
    acc[0] += wgt * bflo(hv.x); acc[1] += wgt * bfhi(hv.x);
    acc[2] += wgt * bflo(hv.y); acc[3] += wgt * bfhi(hv.y);
    acc[4] += wgt * bflo(hv.z); acc[5] += wgt * bfhi(hv.z);
    acc[6] += wgt * bflo(hv.w); acc[7] += wgt * bfhi(hv.w);
    j = jn; s = sn;
  }
  // combine the two half-waves
  S += __shfl_xor(S, 32, 64);
#pragma unroll
  for (int i = 0; i < 8; ++i) acc[i] += __shfl_xor(acc[i], 32, 64);

  const float inv = 1.f / S;
  const int c0 = cl * 8;
  float4 ba = *(const float4*)(b1 + c0);
  float4 bb = *(const float4*)(b1 + c0 + 4);
  float bias[8] = {ba.x, ba.y, ba.z, ba.w, bb.x, bb.y, bb.z, bb.w};
  float4 w0 = *(const float4*)(W2 + c0 * 2);
  float4 w1 = *(const float4*)(W2 + c0 * 2 + 4);
  float4 w2 = *(const float4*)(W2 + c0 * 2 + 8);
  float4 w3 = *(const float4*)(W2 + c0 * 2 + 12);
  float wa[16] = {w0.x, w0.y, w0.z, w0.w, w1.x, w1.y, w1.z, w1.w,
                  w2.x, w2.y, w2.z, w2.w, w3.x, w3.y, w3.z, w3.w};
  float p0 = 0.f, p1 = 0.f;
#pragma unroll
  for (int i = 0; i < 8; ++i) {
    float v = acc[i] * inv + bias[i];
    v = v > 0.f ? v : 0.f;
    p0 += v * wa[2 * i];
    p1 += v * wa[2 * i + 1];
  }
#pragma unroll
  for (int m = 1; m < 32; m <<= 1) {
    p0 += __shfl_xor(p0, m, 64);
    p1 += __shfl_xor(p1, m, 64);
  }
  if (lane == 0) {
    h2c[d] = make_float4(p0, p1,
                         p0 * a_s2[0] + p1 * a_s2[1],
                         p0 * a_d2[0] + p1 * a_d2[1]);
  }
}

// ------- layer-2 aggregate -> out (4 threads per dst, shfl combine) -------
__global__ __launch_bounds__(256) void k_agg2(
    const float4* __restrict__ h2c, const int* __restrict__ rowptr,
    const int* __restrict__ esrc, const float* __restrict__ b2,
    float* __restrict__ out) {
  const int t = threadIdx.x;
  const int g = t & 3;
  const int d = (int)blockIdx.x * 64 + (t >> 2);
  if (d >= NNODE) return;
  const float ald = h2c[d].w;
  const int begin = rowptr[d], end = rowptr[d + 1];
  float S = 0.f, a0 = 0.f, a1 = 0.f;
  for (int j = begin + g; j < end; j += 4) {
    int s = esrc[j];
    float4 v = h2c[s];
    float e = v.z + ald;
    e = fmaxf(e, 0.2f * e);
    float wgt = __expf(e);
    S += wgt;
    a0 += wgt * v.x;
    a1 += wgt * v.y;
  }
  S  += __shfl_xor(S, 1, 64);  S  += __shfl_xor(S, 2, 64);
  a0 += __shfl_xor(a0, 1, 64); a0 += __shfl_xor(a0, 2, 64);
  a1 += __shfl_xor(a1, 1, 64); a1 += __shfl_xor(a1, 2, 64);
  if (g == 0) {
    float inv = 1.f / S;
    out[d * 2 + 0] = a0 * inv + b2[0];
    out[d * 2 + 1] = a1 * inv + b2[1];
  }
}

static inline size_t algn(size_t x) { return (x + 255) & ~(size_t)255; }

extern "C" void kernel_launch(void* const* d_in, const int* in_sizes, int n_in,
                              void* d_out, int out_size, void* d_ws, size_t ws_size,
                              hipStream_t stream) {
  const float* x    = (const float*)d_in[0];
  const int*   ei   = (const int*)d_in[1];
  const float* W1   = (const float*)d_in[2];
  const float* a_s1 = (const float*)d_in[3];
  const float* a_d1 = (const float*)d_in[4];
  const float* b1   = (const float*)d_in[5];
  const float* W2   = (const float*)d_in[6];
  const float* a_s2 = (const float*)d_in[7];
  const float* a_d2 = (const float*)d_in[8];
  const float* b2   = (const float*)d_in[9];
  float* out = (float*)d_out;

  char* w = (char*)d_ws;
  size_t o = 0;
  unsigned short* h1b = (unsigned short*)(w + o); o += algn((size_t)NNODE * 256 * 2);
  unsigned short* W1bT = (unsigned short*)(w + o); o += algn((size_t)256 * 128 * 2);
  float* als1 = (float*)(w + o); o += algn((size_t)NNODE * 4 * 4);
  float* ald1 = (float*)(w + o); o += algn((size_t)NNODE * 4 * 4);
  int*   deg  = (int*)(w + o);   o += algn((size_t)NNODE * 4);
  int*   rowp = (int*)(w + o);   o += algn((size_t)(NNODE + 1) * 4);
  int*   rowf = (int*)(w + o);   o += algn((size_t)(NNODE + 1) * 4);
  int*   rank = (int*)(w + o);   o += algn((size_t)NTOT * 4);
  int*   esrc = (int*)(w + o);   o += algn((size_t)NTOT * 4);
  int*   csum = (int*)(w + o);   o += 1024;
  float4* h2c = (float4*)(w + o); o += algn((size_t)NNODE * 16);
  (void)ws_size; (void)n_in; (void)in_sizes; (void)out_size;

  k_prep<<<dim3(32 + 196), dim3(256), 0, stream>>>(W1, W1bT, deg);
  k_gemm_deg<<<dim3(NB_FUSED), dim3(256), 0, stream>>>(
      x, W1bT, a_s1, a_d1, h1b, als1, ald1, ei, deg, rank);
  k_scan1<<<dim3(NCHUNK), dim3(256), 0, stream>>>(deg, rowp, csum);
  k_scanscatter<<<dim3((NTOT + 255) / 256), dim3(256), 0, stream>>>(
      ei, rowp, csum, rank, rowf, esrc);
  k_agg1<<<dim3(12500), dim3(256), 0, stream>>>(h1b, als1, ald1, rowf, esrc, b1,
                                                W2, a_s2, a_d2, h2c);
  k_agg2<<<dim3((NNODE + 63) / 64), dim3(256), 0, stream>>>(h2c, rowf, esrc, b2, out);
}